// Round 12
// baseline (1407.711 us; speedup 1.0000x reference)
//
#include <hip/hip_runtime.h>
#include <math.h>

#define NB 32      // batch
#define NS 64      // src len
#define NT 64      // trg len
#define NHD 1024   // dec hidden
#define NV 32000
#define NR 2016    // (NT-1)*NB
#define NCT 250    // 32000/128
#define RECB 64    // recurrence blocks

typedef unsigned short u16;
typedef __bf16 bf16x8 __attribute__((ext_vector_type(8)));
typedef float f32x4 __attribute__((ext_vector_type(4)));
typedef unsigned u32x4 __attribute__((ext_vector_type(4)));
#define MFMA16 __builtin_amdgcn_mfma_f32_16x16x32_bf16

__device__ __forceinline__ float sigmf(float x) { return 1.f / (1.f + expf(-x)); }
__device__ __forceinline__ u16 f2bf(float f) {
  union { float f; unsigned u; } v; v.f = f;
  unsigned r = v.u + 0x7FFFu + ((v.u >> 16) & 1u);
  return (u16)(r >> 16);
}
__device__ __forceinline__ float bf2f(u16 h) {
  union { unsigned u; float f; } v; v.u = ((unsigned)h) << 16; return v.f;
}

// ---- coherent (cache-bypassing) loads/stores for cross-block data ----
__device__ __forceinline__ u32x4 ldg_coh(const void* p) {
  u32x4 v;
  asm volatile("global_load_dwordx4 %0, %1, off sc0 sc1" : "=v"(v) : "v"(p));
  return v;  // NOT valid until an explicit s_waitcnt vmcnt(0)
}
__device__ __forceinline__ void stg_coh_u32(void* p, unsigned v) {
  asm volatile("global_store_dword %0, %1, off sc0 sc1" :: "v"(p), "v"(v) : "memory");
}
__device__ __forceinline__ unsigned ldg_coh_u32_wait(const void* p) {
  unsigned v;
  asm volatile("global_load_dword %0, %1, off sc0 sc1\n\ts_waitcnt vmcnt(0)"
               : "=v"(v) : "v"(p) : "memory");
  return v;
}
__device__ __forceinline__ void vmwait0() {
  asm volatile("s_waitcnt vmcnt(0)" ::: "memory");
}

__device__ __forceinline__ void cvt8(const float* __restrict__ in, u16* __restrict__ out, long i) {
  float4 a = *(const float4*)(in + i);
  float4 b = *(const float4*)(in + i + 4);
  union { u16 h[8]; uint4 v; } u;
  u.h[0]=f2bf(a.x); u.h[1]=f2bf(a.y); u.h[2]=f2bf(a.z); u.h[3]=f2bf(a.w);
  u.h[4]=f2bf(b.x); u.h[5]=f2bf(b.y); u.h[6]=f2bf(b.z); u.h[7]=f2bf(b.w);
  *(uint4*)(out + i) = u.v;
}

// ---------------- fused prologue: gathers + weight cvts + dec-frag + rowmap + flags ----------------
__global__ __launch_bounds__(256) void prep_kernel(
    const int* __restrict__ src_tokens, const int* __restrict__ trg_tokens,
    const int* __restrict__ trg_lens,
    const float* __restrict__ src_emb, const float* __restrict__ trg_emb,
    const float* __restrict__ We_ih, const float* __restrict__ Wr_ih,
    const float* __restrict__ Wd_ih, const float* __restrict__ We_hh,
    const float* __restrict__ Wr_hh, const float* __restrict__ Wd_hh,
    u16* __restrict__ xsrcb, u16* __restrict__ xtrgb,
    u16* __restrict__ Wihe, u16* __restrict__ Wihr, u16* __restrict__ Wihd,
    u16* __restrict__ Wbf_e, u16* __restrict__ Wfragd,
    unsigned* __restrict__ rowmap, unsigned* __restrict__ mcnt, unsigned* __restrict__ flags) {
  int b = blockIdx.x, tid = threadIdx.x;
  if (b < 512) {                       // gather_src: 2048*64 chunks
    int idx = b * 256 + tid;
    int m = idx >> 6, c8 = (idx & 63) * 8;
    const float4* s = (const float4*)(src_emb + (size_t)src_tokens[m] * 512 + c8);
    float4 a = s[0], bb = s[1];
    union { u16 h[8]; uint4 v; } u;
    u.h[0]=f2bf(a.x); u.h[1]=f2bf(a.y); u.h[2]=f2bf(a.z); u.h[3]=f2bf(a.w);
    u.h[4]=f2bf(bb.x); u.h[5]=f2bf(bb.y); u.h[6]=f2bf(bb.z); u.h[7]=f2bf(bb.w);
    *(uint4*)(xsrcb + (size_t)m * 512 + c8) = u.v;
  } else if (b < 1016) {               // gather_trg: NR*64 = 129024 = 504*256 chunks
    int idx = (b - 512) * 256 + tid;
    int m = idx >> 6, c8 = (idx & 63) * 8;
    int t = m >> 5, bb2 = m & 31;
    int token = trg_tokens[bb2 * NT + t];
    const float4* s = (const float4*)(trg_emb + (size_t)token * 512 + c8);
    float4 a = s[0], bb = s[1];
    union { u16 h[8]; uint4 v; } u;
    u.h[0]=f2bf(a.x); u.h[1]=f2bf(a.y); u.h[2]=f2bf(a.z); u.h[3]=f2bf(a.w);
    u.h[4]=f2bf(bb.x); u.h[5]=f2bf(bb.y); u.h[6]=f2bf(bb.z); u.h[7]=f2bf(bb.w);
    *(uint4*)(xtrgb + (size_t)m * 512 + c8) = u.v;
  } else if (b < 1528) {               // We_ih -> Wihe (2048*512 = 512 blocks * 256 * 8)
    cvt8(We_ih, Wihe, ((long)(b - 1016) * 256 + tid) * 8);
  } else if (b < 2040) {               // Wr_ih -> Wihr
    cvt8(Wr_ih, Wihr, ((long)(b - 1528) * 256 + tid) * 8);
  } else if (b < 3064) {               // Wd_ih -> Wihd (4096*512 = 1024 blocks)
    cvt8(Wd_ih, Wihd, ((long)(b - 2040) * 256 + tid) * 8);
  } else if (b < 3576) {               // We_hh -> Wbf_e[0:]
    cvt8(We_hh, Wbf_e, ((long)(b - 3064) * 256 + tid) * 8);
  } else if (b < 4088) {               // Wr_hh -> Wbf_e[2048*512:]
    cvt8(Wr_hh, Wbf_e + (size_t)2048 * 512, ((long)(b - 3576) * 256 + tid) * 8);
  } else if (b < 6136) {               // Wd_hh -> dec fragment layout (524288 chunks)
    int idx = (b - 4088) * 256 + tid;
    int lane = idx & 63;
    int kk = (idx >> 6) & 31;
    int g = (idx >> 11) & 3;
    int jt = idx >> 13;
    int row = g * 1024 + jt * 16 + (lane & 15);
    int col = kk * 32 + (lane >> 4) * 8;
    const float4* s = (const float4*)(Wd_hh + (size_t)row * NHD + col);
    float4 a = s[0], bb = s[1];
    union { u16 h[8]; uint4 v; } u;
    u.h[0]=f2bf(a.x); u.h[1]=f2bf(a.y); u.h[2]=f2bf(a.z); u.h[3]=f2bf(a.w);
    u.h[4]=f2bf(bb.x); u.h[5]=f2bf(bb.y); u.h[6]=f2bf(bb.z); u.h[7]=f2bf(bb.w);
    *(uint4*)(Wfragd + (size_t)idx * 8) = u.v;
  } else if (b == 6136) {              // rowmap + mcnt
    __shared__ unsigned P[32];
    for (int i = tid; i < 2048; i += 256) rowmap[i] = 0u;
    if (tid == 0) {
      unsigned acc = 0;
      for (int bb2 = 0; bb2 < 32; bb2++) {
        P[bb2] = acc;
        int L = trg_lens[bb2]; if (L > NT) L = NT;
        acc += (unsigned)(L - 1);
      }
      mcnt[0] = acc;
    }
    __syncthreads();
    for (int bb2 = 0; bb2 < 32; bb2++) {
      int L = trg_lens[bb2]; if (L > NT) L = NT;
      int Lb = L - 1;
      if (tid < Lb) rowmap[P[bb2] + tid] = (unsigned)(tid * 32 + bb2);
    }
  } else {                             // b == 6137: flag init
    flags[tid] = 0u;
  }
}

// ---------------- combined input-gate GEMMs (Aef | Aer | Ad) ----------------
__global__ __launch_bounds__(256) void mfma_gemm3(
    const u16* __restrict__ xsrcb, const u16* __restrict__ xtrgb,
    const u16* __restrict__ Wihe, const u16* __restrict__ Wihr, const u16* __restrict__ Wihd,
    const float* __restrict__ be_ih, const float* __restrict__ be_hh,
    const float* __restrict__ br_ih, const float* __restrict__ br_hh,
    const float* __restrict__ bd_ih, const float* __restrict__ bd_hh,
    float* __restrict__ Aef, float* __restrict__ Aer, float* __restrict__ Ad) {
  int by = blockIdx.y;
  const u16 *A, *Bm; const float *b0, *b1; float* C; int M, N, colTile;
  if (by < 16)      { A = xsrcb; Bm = Wihe; b0 = be_ih; b1 = be_hh; C = Aef; M = 2048; N = 2048; colTile = by; }
  else if (by < 32) { A = xsrcb; Bm = Wihr; b0 = br_ih; b1 = br_hh; C = Aer; M = 2048; N = 2048; colTile = by - 16; }
  else              { A = xtrgb; Bm = Wihd; b0 = bd_ih; b1 = bd_hh; C = Ad;  M = NR;   N = 4096; colTile = by - 32; }
  int tid = threadIdx.x, wave = tid >> 6, lane = tid & 63;
  int r = lane & 15, q = lane >> 4;
  int mh = wave >> 1, nh = wave & 1;
  int rowbase = blockIdx.x * 128 + mh * 64;
  int colbase = colTile * 128 + nh * 64;
  f32x4 acc[4][4] = {};
  for (int k0 = 0; k0 < 512; k0 += 32) {
    bf16x8 a[4], b[4];
#pragma unroll
    for (int mt = 0; mt < 4; mt++) {
      int rb = rowbase + mt * 16 + r;
      if (rb >= M) rb = 0;
      a[mt] = *(const bf16x8*)(A + (size_t)rb * 512 + k0 + q * 8);
    }
#pragma unroll
    for (int nt = 0; nt < 4; nt++)
      b[nt] = *(const bf16x8*)(Bm + (size_t)(colbase + nt * 16 + r) * 512 + k0 + q * 8);
#pragma unroll
    for (int mt = 0; mt < 4; mt++)
#pragma unroll
      for (int nt = 0; nt < 4; nt++)
        acc[mt][nt] = MFMA16(a[mt], b[nt], acc[mt][nt], 0, 0, 0);
  }
#pragma unroll
  for (int nt = 0; nt < 4; nt++) {
    int gn = colbase + nt * 16 + r;
    float bb = b0[gn] + b1[gn];
#pragma unroll
    for (int mt = 0; mt < 4; mt++)
#pragma unroll
      for (int j = 0; j < 4; j++) {
        int gm = rowbase + mt * 16 + q * 4 + j;
        if (gm < M) C[(size_t)gm * N + gn] = acc[mt][nt][j] + bb;
      }
  }
}

// ---------------- persistent recurrence (R10 known-good, unchanged) ----------------
#define ENC_H_OFF 65536
#define ENC_G_OFF 98304
#define DEC_G_OFF 65536
__global__ __launch_bounds__(256, 1) void recurrence_kernel(
    const u16* __restrict__ Wbf_e,    // [4096][512] (fwd 0..2047, rev 2048..)
    const u16* __restrict__ Wfragd,   // dec W fragment layout, 8MB
    const float* __restrict__ Aef, const float* __restrict__ Aer, const float* __restrict__ Ad,
    const int* __restrict__ src_lens,
    u16* __restrict__ ssb, float* __restrict__ hs_dec, u16* __restrict__ Ybf,
    u16* __restrict__ hbf_e,   // [2 parity][2 lstm][32][512] bf16 (coherent)
    u16* __restrict__ hbf_d,   // [2 parity][32][1024] bf16 (coherent)
    unsigned* flags) {
  __shared__ __align__(16) char smem[107008];
  const int tid = threadIdx.x, bid = blockIdx.x;
  const int wave = tid >> 6, lane = tid & 63;
  const int r = lane & 15, q = lane >> 4;
  const int g = wave;
  const int ob = tid >> 3;        // epilogue batch
  const int oj = (tid & 7) * 2;   // epilogue col pair within 16
  const int slen_ob = src_lens[ob];
  unsigned tgt = 0;

#define FLAGBAR(fbase, fcnt)                                                        \
  do {                                                                              \
    tgt++;                                                                          \
    vmwait0();                                                                      \
    __syncthreads();                                                                \
    if (wave == 0) {                                                                \
      if (lane == 0) stg_coh_u32(flags + bid, tgt);                                 \
      unsigned fv = tgt;                                                            \
      do {                                                                          \
        if (lane < (fcnt)) fv = ldg_coh_u32_wait(flags + (fbase) + lane);           \
      } while (__any(fv < tgt));                                                    \
    }                                                                               \
    __syncthreads();                                                                \
  } while (0)

  // ================= encoder =================
  {
    const int lstm = bid >> 5, jt = bid & 31;
    float* gates = (float*)(smem + ENC_G_OFF);
    for (int c = tid; c < 64 * 64; c += 256) {
      int lr = c >> 6, c8 = (c & 63) * 8;
      int grow = lstm * 2048 + (lr >> 4) * 512 + jt * 16 + (lr & 15);
      uint4 v = *(const uint4*)(Wbf_e + (size_t)grow * 512 + c8);
      *(uint4*)(smem + ((lr * 1024 + c8 * 2) ^ ((lr & 7) << 4))) = v;
    }
    const float* Ae = lstm ? Aer : Aef;
    const int jcol = jt * 16 + oj;
    float creg0 = 0.f, creg1 = 0.f;
    for (int t = 0; t < NS; t++) {
      size_t abase = ((size_t)ob * NS + t) * 2048;
      float2 vi = *(const float2*)(Ae + abase + jcol);
      float2 vf = *(const float2*)(Ae + abase + 512 + jcol);
      float2 vg = *(const float2*)(Ae + abase + 1024 + jcol);
      float2 vo = *(const float2*)(Ae + abase + 1536 + jcol);
      if (t == 0) {
        u32x4 z = {0u, 0u, 0u, 0u};
#pragma unroll
        for (int k = 0; k < 8; k++) {
          int c = tid + k * 256;
          int hr = c >> 6, seg = c & 63;
          *(u32x4*)(smem + (ENC_H_OFF + ((hr * 1024 + seg * 16) ^ ((hr & 7) << 4)))) = z;
        }
      } else {
        const u16* hsrc = hbf_e + ((size_t)(t & 1) * 2 + lstm) * 16384;
        u32x4 hv[8];
#pragma unroll
        for (int k = 0; k < 8; k++) hv[k] = ldg_coh(hsrc + (tid + k * 256) * 8);
        vmwait0();
#pragma unroll
        for (int k = 0; k < 8; k++) {
          int c = tid + k * 256;
          int hr = c >> 6, seg = c & 63;
          *(u32x4*)(smem + (ENC_H_OFF + ((hr * 1024 + seg * 16) ^ ((hr & 7) << 4)))) = hv[k];
        }
      }
      __syncthreads();
      f32x4 acc0 = {0.f,0.f,0.f,0.f}, acc1 = {0.f,0.f,0.f,0.f};
      for (int ks = 0; ks < 512; ks += 32) {
        int col2 = (ks + q * 8) * 2;
        int a0r = r, a1r = 16 + r, br = g * 16 + r;
        bf16x8 a0 = *(const bf16x8*)(smem + (ENC_H_OFF + ((a0r * 1024 + col2) ^ ((a0r & 7) << 4))));
        bf16x8 a1 = *(const bf16x8*)(smem + (ENC_H_OFF + ((a1r * 1024 + col2) ^ ((a1r & 7) << 4))));
        bf16x8 bf = *(const bf16x8*)(smem + ((br * 1024 + col2) ^ ((br & 7) << 4)));
        acc0 = MFMA16(a0, bf, acc0, 0, 0, 0);
        acc1 = MFMA16(a1, bf, acc1, 0, 0, 0);
      }
#pragma unroll
      for (int j = 0; j < 4; j++) {
        gates[(g * 32 + q * 4 + j) * 17 + r] = acc0[j];
        gates[(g * 32 + 16 + q * 4 + j) * 17 + r] = acc1[j];
      }
      __syncthreads();
      {
        float I0 = vi.x + gates[(0 * 32 + ob) * 17 + oj];
        float I1 = vi.y + gates[(0 * 32 + ob) * 17 + oj + 1];
        float F0 = vf.x + gates[(1 * 32 + ob) * 17 + oj];
        float F1 = vf.y + gates[(1 * 32 + ob) * 17 + oj + 1];
        float G0 = vg.x + gates[(2 * 32 + ob) * 17 + oj];
        float G1 = vg.y + gates[(2 * 32 + ob) * 17 + oj + 1];
        float O0 = vo.x + gates[(3 * 32 + ob) * 17 + oj];
        float O1 = vo.y + gates[(3 * 32 + ob) * 17 + oj + 1];
        float c0 = sigmf(F0) * creg0 + sigmf(I0) * tanhf(G0);
        float c1 = sigmf(F1) * creg1 + sigmf(I1) * tanhf(G1);
        float h0 = sigmf(O0) * tanhf(c0);
        float h1 = sigmf(O1) * tanhf(c1);
        creg0 = c0; creg1 = c1;
        unsigned hv2 = ((unsigned)f2bf(h1) << 16) | f2bf(h0);
        stg_coh_u32(hbf_e + ((size_t)((t + 1) & 1) * 2 + lstm) * 16384 + ob * 512 + jcol, hv2);
        *(unsigned*)(ssb + ((size_t)ob * NS + t) * NHD + lstm * 512 + jcol) = hv2;
        if (t == slen_ob - 1)
          stg_coh_u32(hbf_d + ob * NHD + lstm * 512 + jcol, hv2);
      }
      FLAGBAR(lstm * 32, 32);
    }
  }

  // phase barrier: all encoder output (hbf_d) visible to every block
  FLAGBAR(0, RECB);

  // ================= decoder =================
  {
    const int jt = bid;
    const int jcol = jt * 16 + oj;
    float* gates = (float*)(smem + DEC_G_OFF);
    const u16* wbase = Wfragd + (size_t)(jt * 4 + g) * 16384;
    float cd0 = 0.f, cd1 = 0.f;
    for (int t = 0; t < NT - 1; t++) {
      const float* ad = Ad + ((size_t)t * NB + ob) * 4096;
      float2 vi = *(const float2*)(ad + jcol);
      float2 vf = *(const float2*)(ad + 1024 + jcol);
      float2 vg = *(const float2*)(ad + 2048 + jcol);
      float2 vo = *(const float2*)(ad + 3072 + jcol);
      const u16* hsrc = hbf_d + (size_t)(t & 1) * (32 * NHD);
      {
        u32x4 hv[16];
#pragma unroll
        for (int k = 0; k < 16; k++) hv[k] = ldg_coh(hsrc + (tid + k * 256) * 8);
        vmwait0();
#pragma unroll
        for (int k = 0; k < 16; k++) {
          int c = tid + k * 256;
          int hr = c >> 7, seg = c & 127;
          *(u32x4*)(smem + ((hr * 2048 + seg * 16) ^ ((hr & 7) << 4))) = hv[k];
        }
      }
      __syncthreads();
      f32x4 acc0 = {0.f,0.f,0.f,0.f}, acc1 = {0.f,0.f,0.f,0.f};
      for (int kk = 0; kk < 32; kk++) {
        int colb = (kk * 32 + q * 8) * 2;
        int a0r = r, a1r = 16 + r;
        bf16x8 a0 = *(const bf16x8*)(smem + ((a0r * 2048 + colb) ^ ((a0r & 7) << 4)));
        bf16x8 a1 = *(const bf16x8*)(smem + ((a1r * 2048 + colb) ^ ((a1r & 7) << 4)));
        bf16x8 bf = *(const bf16x8*)(wbase + ((size_t)kk * 64 + lane) * 8);
        acc0 = MFMA16(a0, bf, acc0, 0, 0, 0);
        acc1 = MFMA16(a1, bf, acc1, 0, 0, 0);
      }
#pragma unroll
      for (int j = 0; j < 4; j++) {
        gates[(g * 32 + q * 4 + j) * 17 + r] = acc0[j];
        gates[(g * 32 + 16 + q * 4 + j) * 17 + r] = acc1[j];
      }
      __syncthreads();
      {
        float I0 = vi.x + gates[(0 * 32 + ob) * 17 + oj];
        float I1 = vi.y + gates[(0 * 32 + ob) * 17 + oj + 1];
        float F0 = vf.x + gates[(1 * 32 + ob) * 17 + oj];
        float F1 = vf.y + gates[(1 * 32 + ob) * 17 + oj + 1];
        float G0 = vg.x + gates[(2 * 32 + ob) * 17 + oj];
        float G1 = vg.y + gates[(2 * 32 + ob) * 17 + oj + 1];
        float O0 = vo.x + gates[(3 * 32 + ob) * 17 + oj];
        float O1 = vo.y + gates[(3 * 32 + ob) * 17 + oj + 1];
        float c0 = sigmf(F0) * cd0 + sigmf(I0) * tanhf(G0);
        float c1 = sigmf(F1) * cd1 + sigmf(I1) * tanhf(G1);
        float h0 = sigmf(O0) * tanhf(c0);
        float h1 = sigmf(O1) * tanhf(c1);
        cd0 = c0; cd1 = c1;
        size_t rowY = (size_t)t * NB + ob;
        unsigned hv2 = ((unsigned)f2bf(h1) << 16) | f2bf(h0);
        stg_coh_u32(hbf_d + (size_t)((t + 1) & 1) * (32 * NHD) + ob * NHD + jcol, hv2);
        *(unsigned*)(Ybf + rowY * 2048 + jcol) = hv2;
        float2 hvf; hvf.x = h0; hvf.y = h1;
        *(float2*)(hs_dec + rowY * NHD + jcol) = hvf;
      }
      if (t != NT - 2) FLAGBAR(0, RECB);
    }
  }
#undef FLAGBAR
}

// ---------------- attention (compact rows) + Wofrag repack rider blocks ----------------
__global__ __launch_bounds__(256) void attn_kernel(const float* __restrict__ hs,
                                                   const u16* __restrict__ ssb,
                                                   const int* __restrict__ src_lens,
                                                   const unsigned* __restrict__ rowmap,
                                                   const unsigned* __restrict__ mcnt,
                                                   const float* __restrict__ W_out,
                                                   u16* __restrict__ Wofrag,
                                                   u16* __restrict__ Ybf) {
  __shared__ __align__(16) float hsh[NHD];
  __shared__ float sc[NS];
  __shared__ float att[NS];
  int tid = threadIdx.x;
  if (blockIdx.x >= NR) {
    // Wofrag repack rider: 128 blocks x 64000 chunks (consumed by gemmlse, stream-ordered)
    long c0 = (long)(blockIdx.x - NR) * 64000;
    for (long idx = c0 + tid; idx < c0 + 64000; idx += 256) {
      int lane2 = (int)(idx & 63);
      int kk = (int)((idx >> 6) & 63);
      long j16 = idx >> 12;
      long row = j16 * 16 + (lane2 & 15);
      int col = kk * 32 + (lane2 >> 4) * 8;
      const float4* s = (const float4*)(W_out + (size_t)row * 2048 + col);
      float4 a = s[0], b = s[1];
      union { u16 h[8]; uint4 v; } u;
      u.h[0]=f2bf(a.x); u.h[1]=f2bf(a.y); u.h[2]=f2bf(a.z); u.h[3]=f2bf(a.w);
      u.h[4]=f2bf(b.x); u.h[5]=f2bf(b.y); u.h[6]=f2bf(b.z); u.h[7]=f2bf(b.w);
      *(uint4*)(Wofrag + (size_t)idx * 8) = u.v;
    }
    return;
  }
  int cr = blockIdx.x;
  if ((unsigned)cr >= mcnt[0]) return;
  int rr = (int)rowmap[cr];
  int b = rr & 31;
  for (int i = tid; i < NHD; i += 256) hsh[i] = hs[(size_t)rr * NHD + i];
  __syncthreads();
  {
    int s = tid >> 2, q = tid & 3;
    const u16* row = ssb + ((size_t)b * NS + s) * NHD + q * 256;
    const float* h4 = hsh + q * 256;
    float p = 0.f;
    for (int k = 0; k < 256; k += 8) {
      uint4 v = *(const uint4*)(row + k);
      p += h4[k + 0] * bf2f((u16)(v.x & 0xFFFF)) + h4[k + 1] * bf2f((u16)(v.x >> 16));
      p += h4[k + 2] * bf2f((u16)(v.y & 0xFFFF)) + h4[k + 3] * bf2f((u16)(v.y >> 16));
      p += h4[k + 4] * bf2f((u16)(v.z & 0xFFFF)) + h4[k + 5] * bf2f((u16)(v.z >> 16));
      p += h4[k + 6] * bf2f((u16)(v.w & 0xFFFF)) + h4[k + 7] * bf2f((u16)(v.w >> 16));
    }
    p += __shfl_xor(p, 1);
    p += __shfl_xor(p, 2);
    if (q == 0) sc[s] = (s < src_lens[b]) ? p : -1e9f;
  }
  __syncthreads();
  if (tid < 64) {
    float v = sc[tid];
    float m = v;
#pragma unroll
    for (int off = 1; off < 64; off <<= 1) m = fmaxf(m, __shfl_xor(m, off));
    float e = expf(v - m);
    float ssum = e;
#pragma unroll
    for (int off = 1; off < 64; off <<= 1) ssum += __shfl_xor(ssum, off);
    att[tid] = e / ssum;
  }
  __syncthreads();
  float a0 = 0, a1 = 0, a2 = 0, a3 = 0;
  int d = tid * 4;
  for (int s2 = 0; s2 < NS; s2++) {
    float a = att[s2];
    uint2 v = *(const uint2*)(ssb + ((size_t)b * NS + s2) * NHD + d);
    a0 += a * bf2f((u16)(v.x & 0xFFFF));
    a1 += a * bf2f((u16)(v.x >> 16));
    a2 += a * bf2f((u16)(v.y & 0xFFFF));
    a3 += a * bf2f((u16)(v.y >> 16));
  }
  ushort4 o;
  o.x = f2bf(a0); o.y = f2bf(a1); o.z = f2bf(a2); o.w = f2bf(a3);
  *(ushort4*)(Ybf + (size_t)rr * 2048 + NHD + d) = o;
}

// ---------------- Ybf -> fragment layout (rowmap folded in) ----------------
__global__ void yfrag_repack(const u16* __restrict__ Ybf, const unsigned* __restrict__ rowmap,
                             u16* __restrict__ out) {
  int idx = blockIdx.x * 256 + threadIdx.x;  // 524288 chunks
  if (idx >= 128 * 64 * 64) return;
  int lane = idx & 63;
  int kk = (idx >> 6) & 63;
  int im = idx >> 12;
  int rr = (int)rowmap[im * 16 + (lane & 15)];
  int col = kk * 32 + (lane >> 4) * 8;
  *(uint4*)(out + (size_t)idx * 8) = *(const uint4*)(Ybf + (size_t)rr * 2048 + col);
}

// ---------------- MFMA logits GEMM (fragment-layout operands) + fused LSE ----------------
__global__ __launch_bounds__(256) void gemmlse_mfma(
    const u16* __restrict__ Yf,   // Yfrag: [128 m-tiles][64 kk][64 lanes][8]
    const u16* __restrict__ Wf,   // Wofrag: [2000 n-tiles][64 kk][64 lanes][8]
    const float* __restrict__ bo, const int* __restrict__ trg_tok,
    const unsigned* __restrict__ rowmap, const unsigned* __restrict__ mcnt,
    float* __restrict__ pm, float* __restrict__ ps, float* __restrict__ tgtlog) {
  __shared__ int tgtc[128];
  __shared__ float pmp[2][128];
  __shared__ float psp[2][128];
  int o = blockIdx.x;
  int u = (o & 7) * 500 + (o >> 3);
  int bm = u & 15, bn = u >> 4;
  const int M = (int)mcnt[0];
  if (bm * 128 >= M) return;
  int tid = threadIdx.x;
  int wave = tid >> 6, lane = tid & 63;
  int r = lane & 15, q = lane >> 4;
  int mh = wave >> 1, nh = wave & 1;
  if (tid < 128) {
    int gm = bm * 128 + tid;
    if (gm < M) {
      int rr = (int)rowmap[gm];
      int tt = rr >> 5, b = rr & 31;
      tgtc[tid] = trg_tok[b * NT + tt + 1];
    } else {
      tgtc[tid] = -1;
    }
  }
  __syncthreads();
  const u16* ybase = Yf + (((size_t)(bm * 8 + mh * 4) * 64) * 64 + lane) * 8;
  const u16* wbase = Wf + (((size_t)(bn * 8 + nh * 4) * 64) * 64 + lane) * 8;
  f32x4 acc[4][4] = {};
  for (int kk = 0; kk < 64; kk += 2) {
    bf16x8 aA[4], bA[4], aB[4], bB[4];
#pragma unroll
    for (int mt = 0; mt < 4; mt++) {
      const u16* p = ybase + ((size_t)mt * 64 + kk) * 512;
      aA[mt] = *(const bf16x8*)(p);
      aB[mt] = *(const bf16x8*)(p + 512);
    }
#pragma unroll
    for (int nt = 0; nt < 4; nt++) {
      const u16* p = wbase + ((size_t)nt * 64 + kk) * 512;
      bA[nt] = *(const bf16x8*)(p);
      bB[nt] = *(const bf16x8*)(p + 512);
    }
#pragma unroll
    for (int mt = 0; mt < 4; mt++)
#pragma unroll
      for (int nt = 0; nt < 4; nt++)
        acc[mt][nt] = MFMA16(aA[mt], bA[nt], acc[mt][nt], 0, 0, 0);
#pragma unroll
    for (int mt = 0; mt < 4; mt++)
#pragma unroll
      for (int nt = 0; nt < 4; nt++)
        acc[mt][nt] = MFMA16(aB[mt], bB[nt], acc[mt][nt], 0, 0, 0);
  }
  int colbase = bn * 128 + nh * 64;
  float bo4[4];
#pragma unroll
  for (int nt = 0; nt < 4; nt++) bo4[nt] = bo[colbase + nt * 16 + r];
#pragma unroll
  for (int mt = 0; mt < 4; mt++)
#pragma unroll
    for (int nt = 0; nt < 4; nt++)
#pragma unroll
      for (int j = 0; j < 4; j++) acc[mt][nt][j] += bo4[nt];
#pragma unroll
  for (int mt = 0; mt < 4; mt++) {
#pragma unroll
    for (int j = 0; j < 4; j++) {
      float m = fmaxf(fmaxf(acc[mt][0][j], acc[mt][1][j]), fmaxf(acc[mt][2][j], acc[mt][3][j]));
      m = fmaxf(m, __shfl_xor(m, 1));
      m = fmaxf(m, __shfl_xor(m, 2));
      m = fmaxf(m, __shfl_xor(m, 4));
      m = fmaxf(m, __shfl_xor(m, 8));
      float s = expf(acc[mt][0][j] - m) + expf(acc[mt][1][j] - m) +
                expf(acc[mt][2][j] - m) + expf(acc[mt][3][j] - m);
      s += __shfl_xor(s, 1);
      s += __shfl_xor(s, 2);
      s += __shfl_xor(s, 4);
      s += __shfl_xor(s, 8);
      int lrow = mh * 64 + mt * 16 + q * 4 + j;
      if (r == 0) { pmp[nh][lrow] = m; psp[nh][lrow] = s; }
      int tc = tgtc[lrow];
      int off = tc - (bn * 128 + nh * 64);
      if (off >= 0 && off < 64 && (off & 15) == r) {
        tgtlog[bm * 128 + lrow] = acc[mt][off >> 4][j];
      }
    }
  }
  __syncthreads();
  if (tid < 128) {
    int gm = bm * 128 + tid;
    if (gm < M) {
      float m0 = pmp[0][tid], m1 = pmp[1][tid];
      float m = fmaxf(m0, m1);
      float s = psp[0][tid] * expf(m0 - m) + psp[1][tid] * expf(m1 - m);
      pm[(size_t)bn * NR + gm] = m;
      ps[(size_t)bn * NR + gm] = s;
    }
  }
}

// ---------------- merge per-chunk lse partials (compact rows) ----------------
__global__ void lse_combine_kernel(const float* __restrict__ pm, const float* __restrict__ ps,
                                   const float* __restrict__ tgtlog,
                                   const unsigned* __restrict__ mcnt,
                                   float* __restrict__ rowval) {
  int cr = blockIdx.x * blockDim.x + threadIdx.x;
  if (cr >= NR) return;
  if ((unsigned)cr >= mcnt[0]) { rowval[cr] = 0.f; return; }
  float m = -1e30f;
  for (int i = 0; i < NCT; i++) m = fmaxf(m, pm[(size_t)i * NR + cr]);
  float s = 0.f;
  for (int i = 0; i < NCT; i++) s += ps[(size_t)i * NR + cr] * expf(pm[(size_t)i * NR + cr] - m);
  float lse = m + logf(s);
  rowval[cr] = tgtlog[cr] - lse;
}

__global__ void final_reduce_kernel(const float* __restrict__ rowval, float* __restrict__ out) {
  __shared__ float sm[256];
  float s = 0.f;
  for (int i = threadIdx.x; i < NR; i += 256) s += rowval[i];
  sm[threadIdx.x] = s;
  __syncthreads();
  for (int off = 128; off > 0; off >>= 1) {
    if (threadIdx.x < off) sm[threadIdx.x] += sm[threadIdx.x + off];
    __syncthreads();
  }
  if (threadIdx.x == 0) out[0] = sm[0];
}

extern "C" void kernel_launch(void* const* d_in, const int* in_sizes, int n_in,
                              void* d_out, int out_size, void* d_ws, size_t ws_size,
                              hipStream_t stream) {
  const int* src_tokens = (const int*)d_in[0];
  const int* src_lens = (const int*)d_in[1];
  const int* trg_tokens = (const int*)d_in[2];
  const int* trg_lens = (const int*)d_in[3];
  const float* src_emb = (const float*)d_in[4];
  const float* trg_emb = (const float*)d_in[5];
  const float* We_ih = (const float*)d_in[6];
  const float* We_hh = (const float*)d_in[7];
  const float* be_ih = (const float*)d_in[8];
  const float* be_hh = (const float*)d_in[9];
  const float* Wr_ih = (const float*)d_in[10];
  const float* Wr_hh = (const float*)d_in[11];
  const float* br_ih = (const float*)d_in[12];
  const float* br_hh = (const float*)d_in[13];
  const float* Wd_ih = (const float*)d_in[14];
  const float* Wd_hh = (const float*)d_in[15];
  const float* bd_ih = (const float*)d_in[16];
  const float* bd_hh = (const float*)d_in[17];
  const float* W_out = (const float*)d_in[18];
  const float* b_out = (const float*)d_in[19];

  char* base = (char*)d_ws;
  size_t off = 0;
  auto alloc = [&](size_t bytes) -> char* {
    char* p = base + off;
    off += (bytes + 255) & ~(size_t)255;
    return p;
  };
  u16* xsrcb = (u16*)alloc((size_t)2048 * 512 * 2);
  u16* xtrgb = (u16*)alloc((size_t)NR * 512 * 2);
  u16* Wihe = (u16*)alloc((size_t)2048 * 512 * 2);
  u16* Wihr = (u16*)alloc((size_t)2048 * 512 * 2);
  u16* Wihd = (u16*)alloc((size_t)4096 * 512 * 2);
  u16* Wbf_e = (u16*)alloc((size_t)4096 * 512 * 2);
  u16* Wfragd = (u16*)alloc((size_t)4096 * 1024 * 2);
  u16* Wofrag = (u16*)alloc((size_t)NV * 2048 * 2);
  u16* Yfrag = (u16*)alloc((size_t)128 * 64 * 64 * 8 * 2);
  float* Aef = (float*)alloc((size_t)2048 * 2048 * 4);
  float* Aer = (float*)alloc((size_t)2048 * 2048 * 4);
  float* Ad  = (float*)alloc((size_t)NR * 4096 * 4);
  u16* ssb  = (u16*)alloc((size_t)NB * NS * NHD * 2);
  float* hs_dec = (float*)alloc((size_t)NR * NHD * 4);
  u16* Ybf = (u16*)alloc((size_t)NR * 2048 * 2);
  u16* hbf_e = (u16*)alloc((size_t)4 * 32 * 512 * 2);
  u16* hbf_d = (u16*)alloc((size_t)2 * 32 * NHD * 2);
  float* pm = (float*)alloc((size_t)NCT * NR * 4);
  float* ps = (float*)alloc((size_t)NCT * NR * 4);
  float* tgtlog = (float*)alloc((size_t)NR * 4);
  float* rowval = (float*)alloc((size_t)NR * 4);
  unsigned* flags = (unsigned*)alloc(1024);
  unsigned* rowmap = (unsigned*)alloc(2048 * 4);
  unsigned* mcnt = (unsigned*)alloc(256);

  // fused prologue: gathers + all weight converts + dec-frag + rowmap + flag init
  prep_kernel<<<6138, 256, 0, stream>>>(
      src_tokens, trg_tokens, trg_lens, src_emb, trg_emb,
      We_ih, Wr_ih, Wd_ih, We_hh, Wr_hh, Wd_hh,
      xsrcb, xtrgb, Wihe, Wihr, Wihd, Wbf_e, Wfragd, rowmap, mcnt, flags);

  // all three input-gate GEMMs in one launch
  mfma_gemm3<<<dim3(16, 64), 256, 0, stream>>>(
      xsrcb, xtrgb, Wihe, Wihr, Wihd,
      be_ih, be_hh, br_ih, br_hh, bd_ih, bd_hh, Aef, Aer, Ad);

  // full recurrence (R10 known-good)
  recurrence_kernel<<<RECB, 256, 0, stream>>>(Wbf_e, Wfragd, Aef, Aer, Ad, src_lens,
                                              ssb, hs_dec, Ybf, hbf_e, hbf_d, flags);

  // attention (compact rows) + Wofrag repack riders
  attn_kernel<<<NR + 128, 256, 0, stream>>>(hs_dec, ssb, src_lens, rowmap, mcnt,
                                            W_out, Wofrag, Ybf);

  // repack Y into fragment layout (rowmap folded in)
  yfrag_repack<<<2048, 256, 0, stream>>>(Ybf, rowmap, Yfrag);

  // fused bf16-MFMA logits GEMM + chunked logsumexp
  gemmlse_mfma<<<4000, 256, 0, stream>>>(Yfrag, Wofrag, b_out, trg_tokens, rowmap, mcnt, pm, ps, tgtlog);
  lse_combine_kernel<<<(NR + 255) / 256, 256, 0, stream>>>(pm, ps, tgtlog, mcnt, rowval);
  final_reduce_kernel<<<1, 256, 0, stream>>>(rowval, (float*)d_out);
}

// Round 13
// 1263.063 us; speedup vs baseline: 1.1145x; 1.1145x over previous
//
#include <hip/hip_runtime.h>
#include <math.h>

#define NB 32      // batch
#define NS 64      // src len
#define NT 64      // trg len
#define NHD 1024   // dec hidden
#define NV 32000
#define NR 2016    // (NT-1)*NB
#define NCT 250    // 32000/128
#define RECB 64    // recurrence blocks

typedef unsigned short u16;
typedef __bf16 bf16x8 __attribute__((ext_vector_type(8)));
typedef float f32x4 __attribute__((ext_vector_type(4)));
typedef unsigned u32x4 __attribute__((ext_vector_type(4)));
#define MFMA16 __builtin_amdgcn_mfma_f32_16x16x32_bf16

__device__ __forceinline__ float sigmf(float x) { return 1.f / (1.f + expf(-x)); }
__device__ __forceinline__ u16 f2bf(float f) {
  union { float f; unsigned u; } v; v.f = f;
  unsigned r = v.u + 0x7FFFu + ((v.u >> 16) & 1u);
  return (u16)(r >> 16);
}
__device__ __forceinline__ float bf2f(u16 h) {
  union { unsigned u; float f; } v; v.u = ((unsigned)h) << 16; return v.f;
}

// ---- coherent (cache-bypassing) loads/stores for cross-block data ----
__device__ __forceinline__ u32x4 ldg_coh(const void* p) {
  u32x4 v;
  asm volatile("global_load_dwordx4 %0, %1, off sc0 sc1" : "=v"(v) : "v"(p));
  return v;  // NOT valid until an explicit s_waitcnt vmcnt(0)
}
__device__ __forceinline__ void stg_coh_u32(void* p, unsigned v) {
  asm volatile("global_store_dword %0, %1, off sc0 sc1" :: "v"(p), "v"(v) : "memory");
}
__device__ __forceinline__ unsigned ldg_coh_u32_wait(const void* p) {
  unsigned v;
  asm volatile("global_load_dword %0, %1, off sc0 sc1\n\ts_waitcnt vmcnt(0)"
               : "=v"(v) : "v"(p) : "memory");
  return v;
}
__device__ __forceinline__ void vmwait0() {
  asm volatile("s_waitcnt vmcnt(0)" ::: "memory");
}

__device__ __forceinline__ void cvt8(const float* __restrict__ in, u16* __restrict__ out, long i) {
  float4 a = *(const float4*)(in + i);
  float4 b = *(const float4*)(in + i + 4);
  union { u16 h[8]; uint4 v; } u;
  u.h[0]=f2bf(a.x); u.h[1]=f2bf(a.y); u.h[2]=f2bf(a.z); u.h[3]=f2bf(a.w);
  u.h[4]=f2bf(b.x); u.h[5]=f2bf(b.y); u.h[6]=f2bf(b.z); u.h[7]=f2bf(b.w);
  *(uint4*)(out + i) = u.v;
}

// ---------------- fused prologue: gathers + weight cvts + dec-frag + rowmap + flags ----------------
__global__ __launch_bounds__(256) void prep_kernel(
    const int* __restrict__ src_tokens, const int* __restrict__ trg_tokens,
    const int* __restrict__ trg_lens,
    const float* __restrict__ src_emb, const float* __restrict__ trg_emb,
    const float* __restrict__ We_ih, const float* __restrict__ Wr_ih,
    const float* __restrict__ Wd_ih, const float* __restrict__ We_hh,
    const float* __restrict__ Wr_hh, const float* __restrict__ Wd_hh,
    u16* __restrict__ xsrcb, u16* __restrict__ xtrgb,
    u16* __restrict__ Wihe, u16* __restrict__ Wihr, u16* __restrict__ Wihd,
    u16* __restrict__ Wbf_e, u16* __restrict__ Wfragd,
    unsigned* __restrict__ rowmap, unsigned* __restrict__ mcnt, unsigned* __restrict__ flags) {
  int b = blockIdx.x, tid = threadIdx.x;
  if (b < 512) {                       // gather_src: 2048*64 chunks
    int idx = b * 256 + tid;
    int m = idx >> 6, c8 = (idx & 63) * 8;
    const float4* s = (const float4*)(src_emb + (size_t)src_tokens[m] * 512 + c8);
    float4 a = s[0], bb = s[1];
    union { u16 h[8]; uint4 v; } u;
    u.h[0]=f2bf(a.x); u.h[1]=f2bf(a.y); u.h[2]=f2bf(a.z); u.h[3]=f2bf(a.w);
    u.h[4]=f2bf(bb.x); u.h[5]=f2bf(bb.y); u.h[6]=f2bf(bb.z); u.h[7]=f2bf(bb.w);
    *(uint4*)(xsrcb + (size_t)m * 512 + c8) = u.v;
  } else if (b < 1016) {               // gather_trg: NR*64 = 129024 = 504*256 chunks
    int idx = (b - 512) * 256 + tid;
    int m = idx >> 6, c8 = (idx & 63) * 8;
    int t = m >> 5, bb2 = m & 31;
    int token = trg_tokens[bb2 * NT + t];
    const float4* s = (const float4*)(trg_emb + (size_t)token * 512 + c8);
    float4 a = s[0], bb = s[1];
    union { u16 h[8]; uint4 v; } u;
    u.h[0]=f2bf(a.x); u.h[1]=f2bf(a.y); u.h[2]=f2bf(a.z); u.h[3]=f2bf(a.w);
    u.h[4]=f2bf(bb.x); u.h[5]=f2bf(bb.y); u.h[6]=f2bf(bb.z); u.h[7]=f2bf(bb.w);
    *(uint4*)(xtrgb + (size_t)m * 512 + c8) = u.v;
  } else if (b < 1528) {               // We_ih -> Wihe
    cvt8(We_ih, Wihe, ((long)(b - 1016) * 256 + tid) * 8);
  } else if (b < 2040) {               // Wr_ih -> Wihr
    cvt8(Wr_ih, Wihr, ((long)(b - 1528) * 256 + tid) * 8);
  } else if (b < 3064) {               // Wd_ih -> Wihd
    cvt8(Wd_ih, Wihd, ((long)(b - 2040) * 256 + tid) * 8);
  } else if (b < 3576) {               // We_hh -> Wbf_e[0:]
    cvt8(We_hh, Wbf_e, ((long)(b - 3064) * 256 + tid) * 8);
  } else if (b < 4088) {               // Wr_hh -> Wbf_e[2048*512:]
    cvt8(Wr_hh, Wbf_e + (size_t)2048 * 512, ((long)(b - 3576) * 256 + tid) * 8);
  } else if (b < 6136) {               // Wd_hh -> dec fragment layout (524288 chunks)
    int idx = (b - 4088) * 256 + tid;
    int lane = idx & 63;
    int kk = (idx >> 6) & 31;
    int g = (idx >> 11) & 3;
    int jt = idx >> 13;
    int row = g * 1024 + jt * 16 + (lane & 15);
    int col = kk * 32 + (lane >> 4) * 8;
    const float4* s = (const float4*)(Wd_hh + (size_t)row * NHD + col);
    float4 a = s[0], bb = s[1];
    union { u16 h[8]; uint4 v; } u;
    u.h[0]=f2bf(a.x); u.h[1]=f2bf(a.y); u.h[2]=f2bf(a.z); u.h[3]=f2bf(a.w);
    u.h[4]=f2bf(bb.x); u.h[5]=f2bf(bb.y); u.h[6]=f2bf(bb.z); u.h[7]=f2bf(bb.w);
    *(uint4*)(Wfragd + (size_t)idx * 8) = u.v;
  } else if (b == 6136) {              // rowmap + mcnt
    __shared__ unsigned P[32];
    for (int i = tid; i < 2048; i += 256) rowmap[i] = 0u;
    if (tid == 0) {
      unsigned acc = 0;
      for (int bb2 = 0; bb2 < 32; bb2++) {
        P[bb2] = acc;
        int L = trg_lens[bb2]; if (L > NT) L = NT;
        acc += (unsigned)(L - 1);
      }
      mcnt[0] = acc;
    }
    __syncthreads();
    for (int bb2 = 0; bb2 < 32; bb2++) {
      int L = trg_lens[bb2]; if (L > NT) L = NT;
      int Lb = L - 1;
      if (tid < Lb) rowmap[P[bb2] + tid] = (unsigned)(tid * 32 + bb2);
    }
  } else {                             // b == 6137: flag init
    flags[tid] = 0u;
  }
}

// ---------------- W_out -> bf16 fragment layout (standalone, full parallelism) ----------------
__global__ void cvt_wo_frag(const float* __restrict__ W, u16* __restrict__ out) {
  long idx = (long)blockIdx.x * 256 + threadIdx.x;  // 8,192,000 chunks
  if (idx >= (long)2000 * 64 * 64) return;
  int lane = (int)(idx & 63);
  int kk = (int)((idx >> 6) & 63);
  long j16 = idx >> 12;
  long row = j16 * 16 + (lane & 15);
  int col = kk * 32 + (lane >> 4) * 8;
  const float4* s = (const float4*)(W + (size_t)row * 2048 + col);
  float4 a = s[0], b = s[1];
  union { u16 h[8]; uint4 v; } u;
  u.h[0]=f2bf(a.x); u.h[1]=f2bf(a.y); u.h[2]=f2bf(a.z); u.h[3]=f2bf(a.w);
  u.h[4]=f2bf(b.x); u.h[5]=f2bf(b.y); u.h[6]=f2bf(b.z); u.h[7]=f2bf(b.w);
  *(uint4*)(out + (size_t)idx * 8) = u.v;
}

// ---------------- combined input-gate GEMMs (Aef | Aer | Ad) ----------------
__global__ __launch_bounds__(256) void mfma_gemm3(
    const u16* __restrict__ xsrcb, const u16* __restrict__ xtrgb,
    const u16* __restrict__ Wihe, const u16* __restrict__ Wihr, const u16* __restrict__ Wihd,
    const float* __restrict__ be_ih, const float* __restrict__ be_hh,
    const float* __restrict__ br_ih, const float* __restrict__ br_hh,
    const float* __restrict__ bd_ih, const float* __restrict__ bd_hh,
    float* __restrict__ Aef, float* __restrict__ Aer, float* __restrict__ Ad) {
  int by = blockIdx.y;
  const u16 *A, *Bm; const float *b0, *b1; float* C; int M, N, colTile;
  if (by < 16)      { A = xsrcb; Bm = Wihe; b0 = be_ih; b1 = be_hh; C = Aef; M = 2048; N = 2048; colTile = by; }
  else if (by < 32) { A = xsrcb; Bm = Wihr; b0 = br_ih; b1 = br_hh; C = Aer; M = 2048; N = 2048; colTile = by - 16; }
  else              { A = xtrgb; Bm = Wihd; b0 = bd_ih; b1 = bd_hh; C = Ad;  M = NR;   N = 4096; colTile = by - 32; }
  int tid = threadIdx.x, wave = tid >> 6, lane = tid & 63;
  int r = lane & 15, q = lane >> 4;
  int mh = wave >> 1, nh = wave & 1;
  int rowbase = blockIdx.x * 128 + mh * 64;
  int colbase = colTile * 128 + nh * 64;
  f32x4 acc[4][4] = {};
  for (int k0 = 0; k0 < 512; k0 += 32) {
    bf16x8 a[4], b[4];
#pragma unroll
    for (int mt = 0; mt < 4; mt++) {
      int rb = rowbase + mt * 16 + r;
      if (rb >= M) rb = 0;
      a[mt] = *(const bf16x8*)(A + (size_t)rb * 512 + k0 + q * 8);
    }
#pragma unroll
    for (int nt = 0; nt < 4; nt++)
      b[nt] = *(const bf16x8*)(Bm + (size_t)(colbase + nt * 16 + r) * 512 + k0 + q * 8);
#pragma unroll
    for (int mt = 0; mt < 4; mt++)
#pragma unroll
      for (int nt = 0; nt < 4; nt++)
        acc[mt][nt] = MFMA16(a[mt], b[nt], acc[mt][nt], 0, 0, 0);
  }
#pragma unroll
  for (int nt = 0; nt < 4; nt++) {
    int gn = colbase + nt * 16 + r;
    float bb = b0[gn] + b1[gn];
#pragma unroll
    for (int mt = 0; mt < 4; mt++)
#pragma unroll
      for (int j = 0; j < 4; j++) {
        int gm = rowbase + mt * 16 + q * 4 + j;
        if (gm < M) C[(size_t)gm * N + gn] = acc[mt][nt][j] + bb;
      }
  }
}

// ---------------- persistent recurrence (R10 known-good; hs_dec store removed) ----------------
#define ENC_H_OFF 65536
#define ENC_G_OFF 98304
#define DEC_G_OFF 65536
__global__ __launch_bounds__(256, 1) void recurrence_kernel(
    const u16* __restrict__ Wbf_e,    // [4096][512] (fwd 0..2047, rev 2048..)
    const u16* __restrict__ Wfragd,   // dec W fragment layout, 8MB
    const float* __restrict__ Aef, const float* __restrict__ Aer, const float* __restrict__ Ad,
    const int* __restrict__ src_lens,
    u16* __restrict__ ssb, u16* __restrict__ Ybf,
    u16* __restrict__ hbf_e,   // [2 parity][2 lstm][32][512] bf16 (coherent)
    u16* __restrict__ hbf_d,   // [2 parity][32][1024] bf16 (coherent)
    unsigned* flags) {
  __shared__ __align__(16) char smem[107008];
  const int tid = threadIdx.x, bid = blockIdx.x;
  const int wave = tid >> 6, lane = tid & 63;
  const int r = lane & 15, q = lane >> 4;
  const int g = wave;
  const int ob = tid >> 3;        // epilogue batch
  const int oj = (tid & 7) * 2;   // epilogue col pair within 16
  const int slen_ob = src_lens[ob];
  unsigned tgt = 0;

#define FLAGBAR(fbase, fcnt)                                                        \
  do {                                                                              \
    tgt++;                                                                          \
    vmwait0();                                                                      \
    __syncthreads();                                                                \
    if (wave == 0) {                                                                \
      if (lane == 0) stg_coh_u32(flags + bid, tgt);                                 \
      unsigned fv = tgt;                                                            \
      do {                                                                          \
        if (lane < (fcnt)) fv = ldg_coh_u32_wait(flags + (fbase) + lane);           \
      } while (__any(fv < tgt));                                                    \
    }                                                                               \
    __syncthreads();                                                                \
  } while (0)

  // ================= encoder =================
  {
    const int lstm = bid >> 5, jt = bid & 31;
    float* gates = (float*)(smem + ENC_G_OFF);
    for (int c = tid; c < 64 * 64; c += 256) {
      int lr = c >> 6, c8 = (c & 63) * 8;
      int grow = lstm * 2048 + (lr >> 4) * 512 + jt * 16 + (lr & 15);
      uint4 v = *(const uint4*)(Wbf_e + (size_t)grow * 512 + c8);
      *(uint4*)(smem + ((lr * 1024 + c8 * 2) ^ ((lr & 7) << 4))) = v;
    }
    const float* Ae = lstm ? Aer : Aef;
    const int jcol = jt * 16 + oj;
    float creg0 = 0.f, creg1 = 0.f;
    for (int t = 0; t < NS; t++) {
      size_t abase = ((size_t)ob * NS + t) * 2048;
      float2 vi = *(const float2*)(Ae + abase + jcol);
      float2 vf = *(const float2*)(Ae + abase + 512 + jcol);
      float2 vg = *(const float2*)(Ae + abase + 1024 + jcol);
      float2 vo = *(const float2*)(Ae + abase + 1536 + jcol);
      if (t == 0) {
        u32x4 z = {0u, 0u, 0u, 0u};
#pragma unroll
        for (int k = 0; k < 8; k++) {
          int c = tid + k * 256;
          int hr = c >> 6, seg = c & 63;
          *(u32x4*)(smem + (ENC_H_OFF + ((hr * 1024 + seg * 16) ^ ((hr & 7) << 4)))) = z;
        }
      } else {
        const u16* hsrc = hbf_e + ((size_t)(t & 1) * 2 + lstm) * 16384;
        u32x4 hv[8];
#pragma unroll
        for (int k = 0; k < 8; k++) hv[k] = ldg_coh(hsrc + (tid + k * 256) * 8);
        vmwait0();
#pragma unroll
        for (int k = 0; k < 8; k++) {
          int c = tid + k * 256;
          int hr = c >> 6, seg = c & 63;
          *(u32x4*)(smem + (ENC_H_OFF + ((hr * 1024 + seg * 16) ^ ((hr & 7) << 4)))) = hv[k];
        }
      }
      __syncthreads();
      f32x4 acc0 = {0.f,0.f,0.f,0.f}, acc1 = {0.f,0.f,0.f,0.f};
      for (int ks = 0; ks < 512; ks += 32) {
        int col2 = (ks + q * 8) * 2;
        int a0r = r, a1r = 16 + r, br = g * 16 + r;
        bf16x8 a0 = *(const bf16x8*)(smem + (ENC_H_OFF + ((a0r * 1024 + col2) ^ ((a0r & 7) << 4))));
        bf16x8 a1 = *(const bf16x8*)(smem + (ENC_H_OFF + ((a1r * 1024 + col2) ^ ((a1r & 7) << 4))));
        bf16x8 bf = *(const bf16x8*)(smem + ((br * 1024 + col2) ^ ((br & 7) << 4)));
        acc0 = MFMA16(a0, bf, acc0, 0, 0, 0);
        acc1 = MFMA16(a1, bf, acc1, 0, 0, 0);
      }
#pragma unroll
      for (int j = 0; j < 4; j++) {
        gates[(g * 32 + q * 4 + j) * 17 + r] = acc0[j];
        gates[(g * 32 + 16 + q * 4 + j) * 17 + r] = acc1[j];
      }
      __syncthreads();
      {
        float I0 = vi.x + gates[(0 * 32 + ob) * 17 + oj];
        float I1 = vi.y + gates[(0 * 32 + ob) * 17 + oj + 1];
        float F0 = vf.x + gates[(1 * 32 + ob) * 17 + oj];
        float F1 = vf.y + gates[(1 * 32 + ob) * 17 + oj + 1];
        float G0 = vg.x + gates[(2 * 32 + ob) * 17 + oj];
        float G1 = vg.y + gates[(2 * 32 + ob) * 17 + oj + 1];
        float O0 = vo.x + gates[(3 * 32 + ob) * 17 + oj];
        float O1 = vo.y + gates[(3 * 32 + ob) * 17 + oj + 1];
        float c0 = sigmf(F0) * creg0 + sigmf(I0) * tanhf(G0);
        float c1 = sigmf(F1) * creg1 + sigmf(I1) * tanhf(G1);
        float h0 = sigmf(O0) * tanhf(c0);
        float h1 = sigmf(O1) * tanhf(c1);
        creg0 = c0; creg1 = c1;
        unsigned hv2 = ((unsigned)f2bf(h1) << 16) | f2bf(h0);
        stg_coh_u32(hbf_e + ((size_t)((t + 1) & 1) * 2 + lstm) * 16384 + ob * 512 + jcol, hv2);
        *(unsigned*)(ssb + ((size_t)ob * NS + t) * NHD + lstm * 512 + jcol) = hv2;
        if (t == slen_ob - 1)
          stg_coh_u32(hbf_d + ob * NHD + lstm * 512 + jcol, hv2);
      }
      FLAGBAR(lstm * 32, 32);
    }
  }

  // phase barrier: all encoder output (hbf_d) visible to every block
  FLAGBAR(0, RECB);

  // ================= decoder =================
  {
    const int jt = bid;
    const int jcol = jt * 16 + oj;
    float* gates = (float*)(smem + DEC_G_OFF);
    const u16* wbase = Wfragd + (size_t)(jt * 4 + g) * 16384;
    float cd0 = 0.f, cd1 = 0.f;
    for (int t = 0; t < NT - 1; t++) {
      const float* ad = Ad + ((size_t)t * NB + ob) * 4096;
      float2 vi = *(const float2*)(ad + jcol);
      float2 vf = *(const float2*)(ad + 1024 + jcol);
      float2 vg = *(const float2*)(ad + 2048 + jcol);
      float2 vo = *(const float2*)(ad + 3072 + jcol);
      const u16* hsrc = hbf_d + (size_t)(t & 1) * (32 * NHD);
      {
        u32x4 hv[16];
#pragma unroll
        for (int k = 0; k < 16; k++) hv[k] = ldg_coh(hsrc + (tid + k * 256) * 8);
        vmwait0();
#pragma unroll
        for (int k = 0; k < 16; k++) {
          int c = tid + k * 256;
          int hr = c >> 7, seg = c & 127;
          *(u32x4*)(smem + ((hr * 2048 + seg * 16) ^ ((hr & 7) << 4))) = hv[k];
        }
      }
      __syncthreads();
      f32x4 acc0 = {0.f,0.f,0.f,0.f}, acc1 = {0.f,0.f,0.f,0.f};
      for (int kk = 0; kk < 32; kk++) {
        int colb = (kk * 32 + q * 8) * 2;
        int a0r = r, a1r = 16 + r;
        bf16x8 a0 = *(const bf16x8*)(smem + ((a0r * 2048 + colb) ^ ((a0r & 7) << 4)));
        bf16x8 a1 = *(const bf16x8*)(smem + ((a1r * 2048 + colb) ^ ((a1r & 7) << 4)));
        bf16x8 bf = *(const bf16x8*)(wbase + ((size_t)kk * 64 + lane) * 8);
        acc0 = MFMA16(a0, bf, acc0, 0, 0, 0);
        acc1 = MFMA16(a1, bf, acc1, 0, 0, 0);
      }
#pragma unroll
      for (int j = 0; j < 4; j++) {
        gates[(g * 32 + q * 4 + j) * 17 + r] = acc0[j];
        gates[(g * 32 + 16 + q * 4 + j) * 17 + r] = acc1[j];
      }
      __syncthreads();
      {
        float I0 = vi.x + gates[(0 * 32 + ob) * 17 + oj];
        float I1 = vi.y + gates[(0 * 32 + ob) * 17 + oj + 1];
        float F0 = vf.x + gates[(1 * 32 + ob) * 17 + oj];
        float F1 = vf.y + gates[(1 * 32 + ob) * 17 + oj + 1];
        float G0 = vg.x + gates[(2 * 32 + ob) * 17 + oj];
        float G1 = vg.y + gates[(2 * 32 + ob) * 17 + oj + 1];
        float O0 = vo.x + gates[(3 * 32 + ob) * 17 + oj];
        float O1 = vo.y + gates[(3 * 32 + ob) * 17 + oj + 1];
        float c0 = sigmf(F0) * cd0 + sigmf(I0) * tanhf(G0);
        float c1 = sigmf(F1) * cd1 + sigmf(I1) * tanhf(G1);
        float h0 = sigmf(O0) * tanhf(c0);
        float h1 = sigmf(O1) * tanhf(c1);
        cd0 = c0; cd1 = c1;
        size_t rowY = (size_t)t * NB + ob;
        unsigned hv2 = ((unsigned)f2bf(h1) << 16) | f2bf(h0);
        stg_coh_u32(hbf_d + (size_t)((t + 1) & 1) * (32 * NHD) + ob * NHD + jcol, hv2);
        *(unsigned*)(Ybf + rowY * 2048 + jcol) = hv2;
      }
      if (t != NT - 2) FLAGBAR(0, RECB);
    }
  }
#undef FLAGBAR
}

// ---------------- attention (compact rows; h read from Ybf bf16) ----------------
__global__ __launch_bounds__(256) void attn_kernel(const u16* __restrict__ Ybf_in,
                                                   const u16* __restrict__ ssb,
                                                   const int* __restrict__ src_lens,
                                                   const unsigned* __restrict__ rowmap,
                                                   const unsigned* __restrict__ mcnt,
                                                   u16* __restrict__ Ybf) {
  __shared__ __align__(16) float hsh[NHD];
  __shared__ float sc[NS];
  __shared__ float att[NS];
  int cr = blockIdx.x;
  if ((unsigned)cr >= mcnt[0]) return;
  int rr = (int)rowmap[cr];
  int b = rr & 31;
  int tid = threadIdx.x;
  {
    int i = tid * 4;  // 256 threads x 4 = 1024
    uint2 v = *(const uint2*)(Ybf_in + (size_t)rr * 2048 + i);
    hsh[i + 0] = bf2f((u16)(v.x & 0xFFFF));
    hsh[i + 1] = bf2f((u16)(v.x >> 16));
    hsh[i + 2] = bf2f((u16)(v.y & 0xFFFF));
    hsh[i + 3] = bf2f((u16)(v.y >> 16));
  }
  __syncthreads();
  {
    int s = tid >> 2, q = tid & 3;
    const u16* row = ssb + ((size_t)b * NS + s) * NHD + q * 256;
    const float* h4 = hsh + q * 256;
    float p = 0.f;
    for (int k = 0; k < 256; k += 8) {
      uint4 v = *(const uint4*)(row + k);
      p += h4[k + 0] * bf2f((u16)(v.x & 0xFFFF)) + h4[k + 1] * bf2f((u16)(v.x >> 16));
      p += h4[k + 2] * bf2f((u16)(v.y & 0xFFFF)) + h4[k + 3] * bf2f((u16)(v.y >> 16));
      p += h4[k + 4] * bf2f((u16)(v.z & 0xFFFF)) + h4[k + 5] * bf2f((u16)(v.z >> 16));
      p += h4[k + 6] * bf2f((u16)(v.w & 0xFFFF)) + h4[k + 7] * bf2f((u16)(v.w >> 16));
    }
    p += __shfl_xor(p, 1);
    p += __shfl_xor(p, 2);
    if (q == 0) sc[s] = (s < src_lens[b]) ? p : -1e9f;
  }
  __syncthreads();
  if (tid < 64) {
    float v = sc[tid];
    float m = v;
#pragma unroll
    for (int off = 1; off < 64; off <<= 1) m = fmaxf(m, __shfl_xor(m, off));
    float e = expf(v - m);
    float ssum = e;
#pragma unroll
    for (int off = 1; off < 64; off <<= 1) ssum += __shfl_xor(ssum, off);
    att[tid] = e / ssum;
  }
  __syncthreads();
  float a0 = 0, a1 = 0, a2 = 0, a3 = 0;
  int d = tid * 4;
  for (int s2 = 0; s2 < NS; s2++) {
    float a = att[s2];
    uint2 v = *(const uint2*)(ssb + ((size_t)b * NS + s2) * NHD + d);
    a0 += a * bf2f((u16)(v.x & 0xFFFF));
    a1 += a * bf2f((u16)(v.x >> 16));
    a2 += a * bf2f((u16)(v.y & 0xFFFF));
    a3 += a * bf2f((u16)(v.y >> 16));
  }
  ushort4 o;
  o.x = f2bf(a0); o.y = f2bf(a1); o.z = f2bf(a2); o.w = f2bf(a3);
  *(ushort4*)(Ybf + (size_t)rr * 2048 + NHD + d) = o;
}

// ---------------- Ybf -> fragment layout (rowmap folded in) ----------------
__global__ void yfrag_repack(const u16* __restrict__ Ybf, const unsigned* __restrict__ rowmap,
                             u16* __restrict__ out) {
  int idx = blockIdx.x * 256 + threadIdx.x;  // 524288 chunks
  if (idx >= 128 * 64 * 64) return;
  int lane = idx & 63;
  int kk = (idx >> 6) & 63;
  int im = idx >> 12;
  int rr = (int)rowmap[im * 16 + (lane & 15)];
  int col = kk * 32 + (lane >> 4) * 8;
  *(uint4*)(out + (size_t)idx * 8) = *(const uint4*)(Ybf + (size_t)rr * 2048 + col);
}

// ---------------- MFMA logits GEMM (fragment-layout operands) + fused LSE ----------------
__global__ __launch_bounds__(256) void gemmlse_mfma(
    const u16* __restrict__ Yf,   // Yfrag: [128 m-tiles][64 kk][64 lanes][8]
    const u16* __restrict__ Wf,   // Wofrag: [2000 n-tiles][64 kk][64 lanes][8]
    const float* __restrict__ bo, const int* __restrict__ trg_tok,
    const unsigned* __restrict__ rowmap, const unsigned* __restrict__ mcnt,
    float* __restrict__ pm, float* __restrict__ ps, float* __restrict__ tgtlog) {
  __shared__ int tgtc[128];
  __shared__ float pmp[2][128];
  __shared__ float psp[2][128];
  int o = blockIdx.x;
  int u = (o & 7) * 500 + (o >> 3);
  int bm = u & 15, bn = u >> 4;
  const int M = (int)mcnt[0];
  if (bm * 128 >= M) return;
  int tid = threadIdx.x;
  int wave = tid >> 6, lane = tid & 63;
  int r = lane & 15, q = lane >> 4;
  int mh = wave >> 1, nh = wave & 1;
  if (tid < 128) {
    int gm = bm * 128 + tid;
    if (gm < M) {
      int rr = (int)rowmap[gm];
      int tt = rr >> 5, b = rr & 31;
      tgtc[tid] = trg_tok[b * NT + tt + 1];
    } else {
      tgtc[tid] = -1;
    }
  }
  __syncthreads();
  const u16* ybase = Yf + (((size_t)(bm * 8 + mh * 4) * 64) * 64 + lane) * 8;
  const u16* wbase = Wf + (((size_t)(bn * 8 + nh * 4) * 64) * 64 + lane) * 8;
  f32x4 acc[4][4] = {};
  for (int kk = 0; kk < 64; kk += 2) {
    bf16x8 aA[4], bA[4], aB[4], bB[4];
#pragma unroll
    for (int mt = 0; mt < 4; mt++) {
      const u16* p = ybase + ((size_t)mt * 64 + kk) * 512;
      aA[mt] = *(const bf16x8*)(p);
      aB[mt] = *(const bf16x8*)(p + 512);
    }
#pragma unroll
    for (int nt = 0; nt < 4; nt++) {
      const u16* p = wbase + ((size_t)nt * 64 + kk) * 512;
      bA[nt] = *(const bf16x8*)(p);
      bB[nt] = *(const bf16x8*)(p + 512);
    }
#pragma unroll
    for (int mt = 0; mt < 4; mt++)
#pragma unroll
      for (int nt = 0; nt < 4; nt++)
        acc[mt][nt] = MFMA16(aA[mt], bA[nt], acc[mt][nt], 0, 0, 0);
#pragma unroll
    for (int mt = 0; mt < 4; mt++)
#pragma unroll
      for (int nt = 0; nt < 4; nt++)
        acc[mt][nt] = MFMA16(aB[mt], bB[nt], acc[mt][nt], 0, 0, 0);
  }
  int colbase = bn * 128 + nh * 64;
  float bo4[4];
#pragma unroll
  for (int nt = 0; nt < 4; nt++) bo4[nt] = bo[colbase + nt * 16 + r];
#pragma unroll
  for (int mt = 0; mt < 4; mt++)
#pragma unroll
    for (int nt = 0; nt < 4; nt++)
#pragma unroll
      for (int j = 0; j < 4; j++) acc[mt][nt][j] += bo4[nt];
#pragma unroll
  for (int mt = 0; mt < 4; mt++) {
#pragma unroll
    for (int j = 0; j < 4; j++) {
      float m = fmaxf(fmaxf(acc[mt][0][j], acc[mt][1][j]), fmaxf(acc[mt][2][j], acc[mt][3][j]));
      m = fmaxf(m, __shfl_xor(m, 1));
      m = fmaxf(m, __shfl_xor(m, 2));
      m = fmaxf(m, __shfl_xor(m, 4));
      m = fmaxf(m, __shfl_xor(m, 8));
      float s = expf(acc[mt][0][j] - m) + expf(acc[mt][1][j] - m) +
                expf(acc[mt][2][j] - m) + expf(acc[mt][3][j] - m);
      s += __shfl_xor(s, 1);
      s += __shfl_xor(s, 2);
      s += __shfl_xor(s, 4);
      s += __shfl_xor(s, 8);
      int lrow = mh * 64 + mt * 16 + q * 4 + j;
      if (r == 0) { pmp[nh][lrow] = m; psp[nh][lrow] = s; }
      int tc = tgtc[lrow];
      int off = tc - (bn * 128 + nh * 64);
      if (off >= 0 && off < 64 && (off & 15) == r) {
        tgtlog[bm * 128 + lrow] = acc[mt][off >> 4][j];
      }
    }
  }
  __syncthreads();
  if (tid < 128) {
    int gm = bm * 128 + tid;
    if (gm < M) {
      float m0 = pmp[0][tid], m1 = pmp[1][tid];
      float m = fmaxf(m0, m1);
      float s = psp[0][tid] * expf(m0 - m) + psp[1][tid] * expf(m1 - m);
      pm[(size_t)bn * NR + gm] = m;
      ps[(size_t)bn * NR + gm] = s;
    }
  }
}

// ---------------- merge per-chunk lse partials (compact rows) ----------------
__global__ void lse_combine_kernel(const float* __restrict__ pm, const float* __restrict__ ps,
                                   const float* __restrict__ tgtlog,
                                   const unsigned* __restrict__ mcnt,
                                   float* __restrict__ rowval) {
  int cr = blockIdx.x * blockDim.x + threadIdx.x;
  if (cr >= NR) return;
  if ((unsigned)cr >= mcnt[0]) { rowval[cr] = 0.f; return; }
  float m = -1e30f;
  for (int i = 0; i < NCT; i++) m = fmaxf(m, pm[(size_t)i * NR + cr]);
  float s = 0.f;
  for (int i = 0; i < NCT; i++) s += ps[(size_t)i * NR + cr] * expf(pm[(size_t)i * NR + cr] - m);
  float lse = m + logf(s);
  rowval[cr] = tgtlog[cr] - lse;
}

__global__ void final_reduce_kernel(const float* __restrict__ rowval, float* __restrict__ out) {
  __shared__ float sm[256];
  float s = 0.f;
  for (int i = threadIdx.x; i < NR; i += 256) s += rowval[i];
  sm[threadIdx.x] = s;
  __syncthreads();
  for (int off = 128; off > 0; off >>= 1) {
    if (threadIdx.x < off) sm[threadIdx.x] += sm[threadIdx.x + off];
    __syncthreads();
  }
  if (threadIdx.x == 0) out[0] = sm[0];
}

extern "C" void kernel_launch(void* const* d_in, const int* in_sizes, int n_in,
                              void* d_out, int out_size, void* d_ws, size_t ws_size,
                              hipStream_t stream) {
  const int* src_tokens = (const int*)d_in[0];
  const int* src_lens = (const int*)d_in[1];
  const int* trg_tokens = (const int*)d_in[2];
  const int* trg_lens = (const int*)d_in[3];
  const float* src_emb = (const float*)d_in[4];
  const float* trg_emb = (const float*)d_in[5];
  const float* We_ih = (const float*)d_in[6];
  const float* We_hh = (const float*)d_in[7];
  const float* be_ih = (const float*)d_in[8];
  const float* be_hh = (const float*)d_in[9];
  const float* Wr_ih = (const float*)d_in[10];
  const float* Wr_hh = (const float*)d_in[11];
  const float* br_ih = (const float*)d_in[12];
  const float* br_hh = (const float*)d_in[13];
  const float* Wd_ih = (const float*)d_in[14];
  const float* Wd_hh = (const float*)d_in[15];
  const float* bd_ih = (const float*)d_in[16];
  const float* bd_hh = (const float*)d_in[17];
  const float* W_out = (const float*)d_in[18];
  const float* b_out = (const float*)d_in[19];

  char* base = (char*)d_ws;
  size_t off = 0;
  auto alloc = [&](size_t bytes) -> char* {
    char* p = base + off;
    off += (bytes + 255) & ~(size_t)255;
    return p;
  };
  u16* xsrcb = (u16*)alloc((size_t)2048 * 512 * 2);
  u16* xtrgb = (u16*)alloc((size_t)NR * 512 * 2);
  u16* Wihe = (u16*)alloc((size_t)2048 * 512 * 2);
  u16* Wihr = (u16*)alloc((size_t)2048 * 512 * 2);
  u16* Wihd = (u16*)alloc((size_t)4096 * 512 * 2);
  u16* Wbf_e = (u16*)alloc((size_t)4096 * 512 * 2);
  u16* Wfragd = (u16*)alloc((size_t)4096 * 1024 * 2);
  u16* Wofrag = (u16*)alloc((size_t)NV * 2048 * 2);
  u16* Yfrag = (u16*)alloc((size_t)128 * 64 * 64 * 8 * 2);
  float* Aef = (float*)alloc((size_t)2048 * 2048 * 4);
  float* Aer = (float*)alloc((size_t)2048 * 2048 * 4);
  float* Ad  = (float*)alloc((size_t)NR * 4096 * 4);
  u16* ssb  = (u16*)alloc((size_t)NB * NS * NHD * 2);
  u16* Ybf = (u16*)alloc((size_t)NR * 2048 * 2);
  u16* hbf_e = (u16*)alloc((size_t)4 * 32 * 512 * 2);
  u16* hbf_d = (u16*)alloc((size_t)2 * 32 * NHD * 2);
  float* pm = (float*)alloc((size_t)NCT * NR * 4);
  float* ps = (float*)alloc((size_t)NCT * NR * 4);
  float* tgtlog = (float*)alloc((size_t)NR * 4);
  float* rowval = (float*)alloc((size_t)NR * 4);
  unsigned* flags = (unsigned*)alloc(1024);
  unsigned* rowmap = (unsigned*)alloc(2048 * 4);
  unsigned* mcnt = (unsigned*)alloc(256);

  // fused prologue: gathers + all weight converts + dec-frag + rowmap + flag init
  prep_kernel<<<6138, 256, 0, stream>>>(
      src_tokens, trg_tokens, trg_lens, src_emb, trg_emb,
      We_ih, Wr_ih, Wd_ih, We_hh, Wr_hh, Wd_hh,
      xsrcb, xtrgb, Wihe, Wihr, Wihd, Wbf_e, Wfragd, rowmap, mcnt, flags);

  // W_out fragment repack (standalone, full parallelism)
  cvt_wo_frag<<<32000, 256, 0, stream>>>(W_out, Wofrag);

  // all three input-gate GEMMs in one launch
  mfma_gemm3<<<dim3(16, 64), 256, 0, stream>>>(
      xsrcb, xtrgb, Wihe, Wihr, Wihd,
      be_ih, be_hh, br_ih, br_hh, bd_ih, bd_hh, Aef, Aer, Ad);

  // full recurrence (R10 known-good; no hs_dec)
  recurrence_kernel<<<RECB, 256, 0, stream>>>(Wbf_e, Wfragd, Aef, Aer, Ad, src_lens,
                                              ssb, Ybf, hbf_e, hbf_d, flags);

  // attention (compact rows; h from Ybf bf16)
  attn_kernel<<<NR, 256, 0, stream>>>(Ybf, ssb, src_lens, rowmap, mcnt, Ybf);

  // repack Y into fragment layout (rowmap folded in)
  yfrag_repack<<<2048, 256, 0, stream>>>(Ybf, rowmap, Yfrag);

  // fused bf16-MFMA logits GEMM + chunked logsumexp
  gemmlse_mfma<<<4000, 256, 0, stream>>>(Yfrag, Wofrag, b_out, trg_tokens, rowmap, mcnt, pm, ps, tgtlog);
  lse_combine_kernel<<<(NR + 255) / 256, 256, 0, stream>>>(pm, ps, tgtlog, mcnt, rowval);
  final_reduce_kernel<<<1, 256, 0, stream>>>(rowval, (float*)d_out);
}

// Round 14
// 1157.589 us; speedup vs baseline: 1.2161x; 1.0911x over previous
//
#include <hip/hip_runtime.h>
#include <math.h>

#define NB 32      // batch
#define NS 64      // src len
#define NT 64      // trg len
#define NHD 1024   // dec hidden
#define NV 32000
#define NR 2016    // (NT-1)*NB
#define NCT 250    // 32000/128
#define RECB 64    // recurrence blocks
#define FSTRIDE 16 // flag stride in u32 (64B: one IF$ line per flag, kills poll contention)

typedef unsigned short u16;
typedef __bf16 bf16x8 __attribute__((ext_vector_type(8)));
typedef float f32x4 __attribute__((ext_vector_type(4)));
typedef unsigned u32x4 __attribute__((ext_vector_type(4)));
#define MFMA16 __builtin_amdgcn_mfma_f32_16x16x32_bf16

__device__ __forceinline__ float sigmf(float x) { return 1.f / (1.f + expf(-x)); }
__device__ __forceinline__ u16 f2bf(float f) {
  union { float f; unsigned u; } v; v.f = f;
  unsigned r = v.u + 0x7FFFu + ((v.u >> 16) & 1u);
  return (u16)(r >> 16);
}
__device__ __forceinline__ float bf2f(u16 h) {
  union { unsigned u; float f; } v; v.u = ((unsigned)h) << 16; return v.f;
}

// ---- coherent (cache-bypassing) loads/stores for cross-block data ----
__device__ __forceinline__ u32x4 ldg_coh(const void* p) {
  u32x4 v;
  asm volatile("global_load_dwordx4 %0, %1, off sc0 sc1" : "=v"(v) : "v"(p));
  return v;  // NOT valid until an explicit s_waitcnt vmcnt(0)
}
__device__ __forceinline__ void stg_coh_u32(void* p, unsigned v) {
  asm volatile("global_store_dword %0, %1, off sc0 sc1" :: "v"(p), "v"(v) : "memory");
}
__device__ __forceinline__ unsigned ldg_coh_u32_wait(const void* p) {
  unsigned v;
  asm volatile("global_load_dword %0, %1, off sc0 sc1\n\ts_waitcnt vmcnt(0)"
               : "=v"(v) : "v"(p) : "memory");
  return v;
}
__device__ __forceinline__ void vmwait0() {
  asm volatile("s_waitcnt vmcnt(0)" ::: "memory");
}

__device__ __forceinline__ void cvt8(const float* __restrict__ in, u16* __restrict__ out, long i) {
  float4 a = *(const float4*)(in + i);
  float4 b = *(const float4*)(in + i + 4);
  union { u16 h[8]; uint4 v; } u;
  u.h[0]=f2bf(a.x); u.h[1]=f2bf(a.y); u.h[2]=f2bf(a.z); u.h[3]=f2bf(a.w);
  u.h[4]=f2bf(b.x); u.h[5]=f2bf(b.y); u.h[6]=f2bf(b.z); u.h[7]=f2bf(b.w);
  *(uint4*)(out + i) = u.v;
}

// ---------------- fused prologue: gathers + weight cvts + dec-frag + Wo-frag + rowmap + flags ----------------
__global__ __launch_bounds__(256) void prep_kernel(
    const int* __restrict__ src_tokens, const int* __restrict__ trg_tokens,
    const int* __restrict__ trg_lens,
    const float* __restrict__ src_emb, const float* __restrict__ trg_emb,
    const float* __restrict__ We_ih, const float* __restrict__ Wr_ih,
    const float* __restrict__ Wd_ih, const float* __restrict__ We_hh,
    const float* __restrict__ Wr_hh, const float* __restrict__ Wd_hh,
    const float* __restrict__ W_out,
    u16* __restrict__ xsrcb, u16* __restrict__ xtrgb,
    u16* __restrict__ Wihe, u16* __restrict__ Wihr, u16* __restrict__ Wihd,
    u16* __restrict__ Wbf_e, u16* __restrict__ Wfragd, u16* __restrict__ Wofrag,
    unsigned* __restrict__ rowmap, unsigned* __restrict__ mcnt, unsigned* __restrict__ flags) {
  int b = blockIdx.x, tid = threadIdx.x;
  if (b < 512) {                       // gather_src: 2048*64 chunks
    int idx = b * 256 + tid;
    int m = idx >> 6, c8 = (idx & 63) * 8;
    const float4* s = (const float4*)(src_emb + (size_t)src_tokens[m] * 512 + c8);
    float4 a = s[0], bb = s[1];
    union { u16 h[8]; uint4 v; } u;
    u.h[0]=f2bf(a.x); u.h[1]=f2bf(a.y); u.h[2]=f2bf(a.z); u.h[3]=f2bf(a.w);
    u.h[4]=f2bf(bb.x); u.h[5]=f2bf(bb.y); u.h[6]=f2bf(bb.z); u.h[7]=f2bf(bb.w);
    *(uint4*)(xsrcb + (size_t)m * 512 + c8) = u.v;
  } else if (b < 1016) {               // gather_trg: NR*64 = 129024 = 504*256 chunks
    int idx = (b - 512) * 256 + tid;
    int m = idx >> 6, c8 = (idx & 63) * 8;
    int t = m >> 5, bb2 = m & 31;
    int token = trg_tokens[bb2 * NT + t];
    const float4* s = (const float4*)(trg_emb + (size_t)token * 512 + c8);
    float4 a = s[0], bb = s[1];
    union { u16 h[8]; uint4 v; } u;
    u.h[0]=f2bf(a.x); u.h[1]=f2bf(a.y); u.h[2]=f2bf(a.z); u.h[3]=f2bf(a.w);
    u.h[4]=f2bf(bb.x); u.h[5]=f2bf(bb.y); u.h[6]=f2bf(bb.z); u.h[7]=f2bf(bb.w);
    *(uint4*)(xtrgb + (size_t)m * 512 + c8) = u.v;
  } else if (b < 1528) {               // We_ih -> Wihe
    cvt8(We_ih, Wihe, ((long)(b - 1016) * 256 + tid) * 8);
  } else if (b < 2040) {               // Wr_ih -> Wihr
    cvt8(Wr_ih, Wihr, ((long)(b - 1528) * 256 + tid) * 8);
  } else if (b < 3064) {               // Wd_ih -> Wihd
    cvt8(Wd_ih, Wihd, ((long)(b - 2040) * 256 + tid) * 8);
  } else if (b < 3576) {               // We_hh -> Wbf_e[0:]
    cvt8(We_hh, Wbf_e, ((long)(b - 3064) * 256 + tid) * 8);
  } else if (b < 4088) {               // Wr_hh -> Wbf_e[2048*512:]
    cvt8(Wr_hh, Wbf_e + (size_t)2048 * 512, ((long)(b - 3576) * 256 + tid) * 8);
  } else if (b < 6136) {               // Wd_hh -> dec fragment layout (524288 chunks)
    int idx = (b - 4088) * 256 + tid;
    int lane = idx & 63;
    int kk = (idx >> 6) & 31;
    int g = (idx >> 11) & 3;
    int jt = idx >> 13;
    int row = g * 1024 + jt * 16 + (lane & 15);
    int col = kk * 32 + (lane >> 4) * 8;
    const float4* s = (const float4*)(Wd_hh + (size_t)row * NHD + col);
    float4 a = s[0], bb = s[1];
    union { u16 h[8]; uint4 v; } u;
    u.h[0]=f2bf(a.x); u.h[1]=f2bf(a.y); u.h[2]=f2bf(a.z); u.h[3]=f2bf(a.w);
    u.h[4]=f2bf(bb.x); u.h[5]=f2bf(bb.y); u.h[6]=f2bf(bb.z); u.h[7]=f2bf(bb.w);
    *(uint4*)(Wfragd + (size_t)idx * 8) = u.v;
  } else if (b == 6136) {              // rowmap + mcnt
    __shared__ unsigned P[32];
    for (int i = tid; i < 2048; i += 256) rowmap[i] = 0u;
    if (tid == 0) {
      unsigned acc = 0;
      for (int bb2 = 0; bb2 < 32; bb2++) {
        P[bb2] = acc;
        int L = trg_lens[bb2]; if (L > NT) L = NT;
        acc += (unsigned)(L - 1);
      }
      mcnt[0] = acc;
    }
    __syncthreads();
    for (int bb2 = 0; bb2 < 32; bb2++) {
      int L = trg_lens[bb2]; if (L > NT) L = NT;
      int Lb = L - 1;
      if (tid < Lb) rowmap[P[bb2] + tid] = (unsigned)(tid * 32 + bb2);
    }
  } else if (b == 6137) {              // flag init (spread, 64B stride)
    if (tid < RECB) flags[tid * FSTRIDE] = 0u;
  } else {                             // b >= 6138: W_out -> fragment layout (8,192,000 chunks)
    long idx = (long)(b - 6138) * 256 + tid;
    int lane = (int)(idx & 63);
    int kk = (int)((idx >> 6) & 63);
    long j16 = idx >> 12;
    long row = j16 * 16 + (lane & 15);
    int col = kk * 32 + (lane >> 4) * 8;
    const float4* s = (const float4*)(W_out + (size_t)row * 2048 + col);
    float4 a = s[0], bb = s[1];
    union { u16 h[8]; uint4 v; } u;
    u.h[0]=f2bf(a.x); u.h[1]=f2bf(a.y); u.h[2]=f2bf(a.z); u.h[3]=f2bf(a.w);
    u.h[4]=f2bf(bb.x); u.h[5]=f2bf(bb.y); u.h[6]=f2bf(bb.z); u.h[7]=f2bf(bb.w);
    *(uint4*)(Wofrag + (size_t)idx * 8) = u.v;
  }
}

// ---------------- combined input-gate GEMMs (Aef | Aer | Ad) ----------------
__global__ __launch_bounds__(256) void mfma_gemm3(
    const u16* __restrict__ xsrcb, const u16* __restrict__ xtrgb,
    const u16* __restrict__ Wihe, const u16* __restrict__ Wihr, const u16* __restrict__ Wihd,
    const float* __restrict__ be_ih, const float* __restrict__ be_hh,
    const float* __restrict__ br_ih, const float* __restrict__ br_hh,
    const float* __restrict__ bd_ih, const float* __restrict__ bd_hh,
    float* __restrict__ Aef, float* __restrict__ Aer, float* __restrict__ Ad) {
  int by = blockIdx.y;
  const u16 *A, *Bm; const float *b0, *b1; float* C; int M, N, colTile;
  if (by < 16)      { A = xsrcb; Bm = Wihe; b0 = be_ih; b1 = be_hh; C = Aef; M = 2048; N = 2048; colTile = by; }
  else if (by < 32) { A = xsrcb; Bm = Wihr; b0 = br_ih; b1 = br_hh; C = Aer; M = 2048; N = 2048; colTile = by - 16; }
  else              { A = xtrgb; Bm = Wihd; b0 = bd_ih; b1 = bd_hh; C = Ad;  M = NR;   N = 4096; colTile = by - 32; }
  int tid = threadIdx.x, wave = tid >> 6, lane = tid & 63;
  int r = lane & 15, q = lane >> 4;
  int mh = wave >> 1, nh = wave & 1;
  int rowbase = blockIdx.x * 128 + mh * 64;
  int colbase = colTile * 128 + nh * 64;
  f32x4 acc[4][4] = {};
  for (int k0 = 0; k0 < 512; k0 += 32) {
    bf16x8 a[4], b[4];
#pragma unroll
    for (int mt = 0; mt < 4; mt++) {
      int rb = rowbase + mt * 16 + r;
      if (rb >= M) rb = 0;
      a[mt] = *(const bf16x8*)(A + (size_t)rb * 512 + k0 + q * 8);
    }
#pragma unroll
    for (int nt = 0; nt < 4; nt++)
      b[nt] = *(const bf16x8*)(Bm + (size_t)(colbase + nt * 16 + r) * 512 + k0 + q * 8);
#pragma unroll
    for (int mt = 0; mt < 4; mt++)
#pragma unroll
      for (int nt = 0; nt < 4; nt++)
        acc[mt][nt] = MFMA16(a[mt], b[nt], acc[mt][nt], 0, 0, 0);
  }
#pragma unroll
  for (int nt = 0; nt < 4; nt++) {
    int gn = colbase + nt * 16 + r;
    float bb = b0[gn] + b1[gn];
#pragma unroll
    for (int mt = 0; mt < 4; mt++)
#pragma unroll
      for (int j = 0; j < 4; j++) {
        int gm = rowbase + mt * 16 + q * 4 + j;
        if (gm < M) C[(size_t)gm * N + gn] = acc[mt][nt][j] + bb;
      }
  }
}

// ---------------- persistent recurrence (spread flags) ----------------
#define ENC_H_OFF 65536
#define ENC_G_OFF 98304
#define DEC_G_OFF 65536
__global__ __launch_bounds__(256, 1) void recurrence_kernel(
    const u16* __restrict__ Wbf_e,    // [4096][512] (fwd 0..2047, rev 2048..)
    const u16* __restrict__ Wfragd,   // dec W fragment layout, 8MB
    const float* __restrict__ Aef, const float* __restrict__ Aer, const float* __restrict__ Ad,
    const int* __restrict__ src_lens,
    u16* __restrict__ ssb, u16* __restrict__ Ybf,
    u16* __restrict__ hbf_e,   // [2 parity][2 lstm][32][512] bf16 (coherent)
    u16* __restrict__ hbf_d,   // [2 parity][32][1024] bf16 (coherent)
    unsigned* flags) {
  __shared__ __align__(16) char smem[107008];
  const int tid = threadIdx.x, bid = blockIdx.x;
  const int wave = tid >> 6, lane = tid & 63;
  const int r = lane & 15, q = lane >> 4;
  const int g = wave;
  const int ob = tid >> 3;        // epilogue batch
  const int oj = (tid & 7) * 2;   // epilogue col pair within 16
  const int slen_ob = src_lens[ob];
  unsigned tgt = 0;

#define FLAGBAR(fbase, fcnt)                                                               \
  do {                                                                                     \
    tgt++;                                                                                 \
    vmwait0();                                                                             \
    __syncthreads();                                                                       \
    if (wave == 0) {                                                                       \
      if (lane == 0) stg_coh_u32(flags + bid * FSTRIDE, tgt);                              \
      unsigned fv = tgt;                                                                   \
      do {                                                                                 \
        if (lane < (fcnt)) fv = ldg_coh_u32_wait(flags + ((fbase) + lane) * FSTRIDE);      \
      } while (__any(fv < tgt));                                                           \
    }                                                                                      \
    __syncthreads();                                                                       \
  } while (0)

  // ================= encoder =================
  {
    const int lstm = bid >> 5, jt = bid & 31;
    float* gates = (float*)(smem + ENC_G_OFF);
    for (int c = tid; c < 64 * 64; c += 256) {
      int lr = c >> 6, c8 = (c & 63) * 8;
      int grow = lstm * 2048 + (lr >> 4) * 512 + jt * 16 + (lr & 15);
      uint4 v = *(const uint4*)(Wbf_e + (size_t)grow * 512 + c8);
      *(uint4*)(smem + ((lr * 1024 + c8 * 2) ^ ((lr & 7) << 4))) = v;
    }
    const float* Ae = lstm ? Aer : Aef;
    const int jcol = jt * 16 + oj;
    float creg0 = 0.f, creg1 = 0.f;
    for (int t = 0; t < NS; t++) {
      size_t abase = ((size_t)ob * NS + t) * 2048;
      float2 vi = *(const float2*)(Ae + abase + jcol);
      float2 vf = *(const float2*)(Ae + abase + 512 + jcol);
      float2 vg = *(const float2*)(Ae + abase + 1024 + jcol);
      float2 vo = *(const float2*)(Ae + abase + 1536 + jcol);
      if (t == 0) {
        u32x4 z = {0u, 0u, 0u, 0u};
#pragma unroll
        for (int k = 0; k < 8; k++) {
          int c = tid + k * 256;
          int hr = c >> 6, seg = c & 63;
          *(u32x4*)(smem + (ENC_H_OFF + ((hr * 1024 + seg * 16) ^ ((hr & 7) << 4)))) = z;
        }
      } else {
        const u16* hsrc = hbf_e + ((size_t)(t & 1) * 2 + lstm) * 16384;
        u32x4 hv[8];
#pragma unroll
        for (int k = 0; k < 8; k++) hv[k] = ldg_coh(hsrc + (tid + k * 256) * 8);
        vmwait0();
#pragma unroll
        for (int k = 0; k < 8; k++) {
          int c = tid + k * 256;
          int hr = c >> 6, seg = c & 63;
          *(u32x4*)(smem + (ENC_H_OFF + ((hr * 1024 + seg * 16) ^ ((hr & 7) << 4)))) = hv[k];
        }
      }
      __syncthreads();
      f32x4 acc0 = {0.f,0.f,0.f,0.f}, acc1 = {0.f,0.f,0.f,0.f};
      for (int ks = 0; ks < 512; ks += 32) {
        int col2 = (ks + q * 8) * 2;
        int a0r = r, a1r = 16 + r, br = g * 16 + r;
        bf16x8 a0 = *(const bf16x8*)(smem + (ENC_H_OFF + ((a0r * 1024 + col2) ^ ((a0r & 7) << 4))));
        bf16x8 a1 = *(const bf16x8*)(smem + (ENC_H_OFF + ((a1r * 1024 + col2) ^ ((a1r & 7) << 4))));
        bf16x8 bf = *(const bf16x8*)(smem + ((br * 1024 + col2) ^ ((br & 7) << 4)));
        acc0 = MFMA16(a0, bf, acc0, 0, 0, 0);
        acc1 = MFMA16(a1, bf, acc1, 0, 0, 0);
      }
#pragma unroll
      for (int j = 0; j < 4; j++) {
        gates[(g * 32 + q * 4 + j) * 17 + r] = acc0[j];
        gates[(g * 32 + 16 + q * 4 + j) * 17 + r] = acc1[j];
      }
      __syncthreads();
      {
        float I0 = vi.x + gates[(0 * 32 + ob) * 17 + oj];
        float I1 = vi.y + gates[(0 * 32 + ob) * 17 + oj + 1];
        float F0 = vf.x + gates[(1 * 32 + ob) * 17 + oj];
        float F1 = vf.y + gates[(1 * 32 + ob) * 17 + oj + 1];
        float G0 = vg.x + gates[(2 * 32 + ob) * 17 + oj];
        float G1 = vg.y + gates[(2 * 32 + ob) * 17 + oj + 1];
        float O0 = vo.x + gates[(3 * 32 + ob) * 17 + oj];
        float O1 = vo.y + gates[(3 * 32 + ob) * 17 + oj + 1];
        float c0 = sigmf(F0) * creg0 + sigmf(I0) * tanhf(G0);
        float c1 = sigmf(F1) * creg1 + sigmf(I1) * tanhf(G1);
        float h0 = sigmf(O0) * tanhf(c0);
        float h1 = sigmf(O1) * tanhf(c1);
        creg0 = c0; creg1 = c1;
        unsigned hv2 = ((unsigned)f2bf(h1) << 16) | f2bf(h0);
        stg_coh_u32(hbf_e + ((size_t)((t + 1) & 1) * 2 + lstm) * 16384 + ob * 512 + jcol, hv2);
        *(unsigned*)(ssb + ((size_t)ob * NS + t) * NHD + lstm * 512 + jcol) = hv2;
        if (t == slen_ob - 1)
          stg_coh_u32(hbf_d + ob * NHD + lstm * 512 + jcol, hv2);
      }
      FLAGBAR(lstm * 32, 32);
    }
  }

  // phase barrier: all encoder output (hbf_d) visible to every block
  FLAGBAR(0, RECB);

  // ================= decoder =================
  {
    const int jt = bid;
    const int jcol = jt * 16 + oj;
    float* gates = (float*)(smem + DEC_G_OFF);
    const u16* wbase = Wfragd + (size_t)(jt * 4 + g) * 16384;
    float cd0 = 0.f, cd1 = 0.f;
    for (int t = 0; t < NT - 1; t++) {
      const float* ad = Ad + ((size_t)t * NB + ob) * 4096;
      float2 vi = *(const float2*)(ad + jcol);
      float2 vf = *(const float2*)(ad + 1024 + jcol);
      float2 vg = *(const float2*)(ad + 2048 + jcol);
      float2 vo = *(const float2*)(ad + 3072 + jcol);
      const u16* hsrc = hbf_d + (size_t)(t & 1) * (32 * NHD);
      {
        u32x4 hv[16];
#pragma unroll
        for (int k = 0; k < 16; k++) hv[k] = ldg_coh(hsrc + (tid + k * 256) * 8);
        vmwait0();
#pragma unroll
        for (int k = 0; k < 16; k++) {
          int c = tid + k * 256;
          int hr = c >> 7, seg = c & 127;
          *(u32x4*)(smem + ((hr * 2048 + seg * 16) ^ ((hr & 7) << 4))) = hv[k];
        }
      }
      __syncthreads();
      f32x4 acc0 = {0.f,0.f,0.f,0.f}, acc1 = {0.f,0.f,0.f,0.f};
      for (int kk = 0; kk < 32; kk++) {
        int colb = (kk * 32 + q * 8) * 2;
        int a0r = r, a1r = 16 + r;
        bf16x8 a0 = *(const bf16x8*)(smem + ((a0r * 2048 + colb) ^ ((a0r & 7) << 4)));
        bf16x8 a1 = *(const bf16x8*)(smem + ((a1r * 2048 + colb) ^ ((a1r & 7) << 4)));
        bf16x8 bf = *(const bf16x8*)(wbase + ((size_t)kk * 64 + lane) * 8);
        acc0 = MFMA16(a0, bf, acc0, 0, 0, 0);
        acc1 = MFMA16(a1, bf, acc1, 0, 0, 0);
      }
#pragma unroll
      for (int j = 0; j < 4; j++) {
        gates[(g * 32 + q * 4 + j) * 17 + r] = acc0[j];
        gates[(g * 32 + 16 + q * 4 + j) * 17 + r] = acc1[j];
      }
      __syncthreads();
      {
        float I0 = vi.x + gates[(0 * 32 + ob) * 17 + oj];
        float I1 = vi.y + gates[(0 * 32 + ob) * 17 + oj + 1];
        float F0 = vf.x + gates[(1 * 32 + ob) * 17 + oj];
        float F1 = vf.y + gates[(1 * 32 + ob) * 17 + oj + 1];
        float G0 = vg.x + gates[(2 * 32 + ob) * 17 + oj];
        float G1 = vg.y + gates[(2 * 32 + ob) * 17 + oj + 1];
        float O0 = vo.x + gates[(3 * 32 + ob) * 17 + oj];
        float O1 = vo.y + gates[(3 * 32 + ob) * 17 + oj + 1];
        float c0 = sigmf(F0) * cd0 + sigmf(I0) * tanhf(G0);
        float c1 = sigmf(F1) * cd1 + sigmf(I1) * tanhf(G1);
        float h0 = sigmf(O0) * tanhf(c0);
        float h1 = sigmf(O1) * tanhf(c1);
        cd0 = c0; cd1 = c1;
        size_t rowY = (size_t)t * NB + ob;
        unsigned hv2 = ((unsigned)f2bf(h1) << 16) | f2bf(h0);
        stg_coh_u32(hbf_d + (size_t)((t + 1) & 1) * (32 * NHD) + ob * NHD + jcol, hv2);
        *(unsigned*)(Ybf + rowY * 2048 + jcol) = hv2;
      }
      if (t != NT - 2) FLAGBAR(0, RECB);
    }
  }
#undef FLAGBAR
}

// ---------------- attention (compact rows; h read from Ybf bf16) ----------------
__global__ __launch_bounds__(256) void attn_kernel(const u16* __restrict__ Ybf_in,
                                                   const u16* __restrict__ ssb,
                                                   const int* __restrict__ src_lens,
                                                   const unsigned* __restrict__ rowmap,
                                                   const unsigned* __restrict__ mcnt,
                                                   u16* __restrict__ Ybf) {
  __shared__ __align__(16) float hsh[NHD];
  __shared__ float sc[NS];
  __shared__ float att[NS];
  int cr = blockIdx.x;
  if ((unsigned)cr >= mcnt[0]) return;
  int rr = (int)rowmap[cr];
  int b = rr & 31;
  int tid = threadIdx.x;
  {
    int i = tid * 4;  // 256 threads x 4 = 1024
    uint2 v = *(const uint2*)(Ybf_in + (size_t)rr * 2048 + i);
    hsh[i + 0] = bf2f((u16)(v.x & 0xFFFF));
    hsh[i + 1] = bf2f((u16)(v.x >> 16));
    hsh[i + 2] = bf2f((u16)(v.y & 0xFFFF));
    hsh[i + 3] = bf2f((u16)(v.y >> 16));
  }
  __syncthreads();
  {
    int s = tid >> 2, q = tid & 3;
    const u16* row = ssb + ((size_t)b * NS + s) * NHD + q * 256;
    const float* h4 = hsh + q * 256;
    float p = 0.f;
    for (int k = 0; k < 256; k += 8) {
      uint4 v = *(const uint4*)(row + k);
      p += h4[k + 0] * bf2f((u16)(v.x & 0xFFFF)) + h4[k + 1] * bf2f((u16)(v.x >> 16));
      p += h4[k + 2] * bf2f((u16)(v.y & 0xFFFF)) + h4[k + 3] * bf2f((u16)(v.y >> 16));
      p += h4[k + 4] * bf2f((u16)(v.z & 0xFFFF)) + h4[k + 5] * bf2f((u16)(v.z >> 16));
      p += h4[k + 6] * bf2f((u16)(v.w & 0xFFFF)) + h4[k + 7] * bf2f((u16)(v.w >> 16));
    }
    p += __shfl_xor(p, 1);
    p += __shfl_xor(p, 2);
    if (q == 0) sc[s] = (s < src_lens[b]) ? p : -1e9f;
  }
  __syncthreads();
  if (tid < 64) {
    float v = sc[tid];
    float m = v;
#pragma unroll
    for (int off = 1; off < 64; off <<= 1) m = fmaxf(m, __shfl_xor(m, off));
    float e = expf(v - m);
    float ssum = e;
#pragma unroll
    for (int off = 1; off < 64; off <<= 1) ssum += __shfl_xor(ssum, off);
    att[tid] = e / ssum;
  }
  __syncthreads();
  float a0 = 0, a1 = 0, a2 = 0, a3 = 0;
  int d = tid * 4;
  for (int s2 = 0; s2 < NS; s2++) {
    float a = att[s2];
    uint2 v = *(const uint2*)(ssb + ((size_t)b * NS + s2) * NHD + d);
    a0 += a * bf2f((u16)(v.x & 0xFFFF));
    a1 += a * bf2f((u16)(v.x >> 16));
    a2 += a * bf2f((u16)(v.y & 0xFFFF));
    a3 += a * bf2f((u16)(v.y >> 16));
  }
  ushort4 o;
  o.x = f2bf(a0); o.y = f2bf(a1); o.z = f2bf(a2); o.w = f2bf(a3);
  *(ushort4*)(Ybf + (size_t)rr * 2048 + NHD + d) = o;
}

// ---------------- Ybf -> fragment layout (rowmap folded in) ----------------
__global__ void yfrag_repack(const u16* __restrict__ Ybf, const unsigned* __restrict__ rowmap,
                             u16* __restrict__ out) {
  int idx = blockIdx.x * 256 + threadIdx.x;  // 524288 chunks
  if (idx >= 128 * 64 * 64) return;
  int lane = idx & 63;
  int kk = (idx >> 6) & 63;
  int im = idx >> 12;
  int rr = (int)rowmap[im * 16 + (lane & 15)];
  int col = kk * 32 + (lane >> 4) * 8;
  *(uint4*)(out + (size_t)idx * 8) = *(const uint4*)(Ybf + (size_t)rr * 2048 + col);
}

// ---------------- MFMA logits GEMM (fragment-layout operands) + fused LSE ----------------
__global__ __launch_bounds__(256) void gemmlse_mfma(
    const u16* __restrict__ Yf,   // Yfrag: [128 m-tiles][64 kk][64 lanes][8]
    const u16* __restrict__ Wf,   // Wofrag: [2000 n-tiles][64 kk][64 lanes][8]
    const float* __restrict__ bo, const int* __restrict__ trg_tok,
    const unsigned* __restrict__ rowmap, const unsigned* __restrict__ mcnt,
    float* __restrict__ pm, float* __restrict__ ps, float* __restrict__ tgtlog) {
  __shared__ int tgtc[128];
  __shared__ float pmp[2][128];
  __shared__ float psp[2][128];
  int o = blockIdx.x;
  int u = (o & 7) * 500 + (o >> 3);
  int bm = u & 15, bn = u >> 4;
  const int M = (int)mcnt[0];
  if (bm * 128 >= M) return;
  int tid = threadIdx.x;
  int wave = tid >> 6, lane = tid & 63;
  int r = lane & 15, q = lane >> 4;
  int mh = wave >> 1, nh = wave & 1;
  if (tid < 128) {
    int gm = bm * 128 + tid;
    if (gm < M) {
      int rr = (int)rowmap[gm];
      int tt = rr >> 5, b = rr & 31;
      tgtc[tid] = trg_tok[b * NT + tt + 1];
    } else {
      tgtc[tid] = -1;
    }
  }
  __syncthreads();
  const u16* ybase = Yf + (((size_t)(bm * 8 + mh * 4) * 64) * 64 + lane) * 8;
  const u16* wbase = Wf + (((size_t)(bn * 8 + nh * 4) * 64) * 64 + lane) * 8;
  f32x4 acc[4][4] = {};
  for (int kk = 0; kk < 64; kk += 2) {
    bf16x8 aA[4], bA[4], aB[4], bB[4];
#pragma unroll
    for (int mt = 0; mt < 4; mt++) {
      const u16* p = ybase + ((size_t)mt * 64 + kk) * 512;
      aA[mt] = *(const bf16x8*)(p);
      aB[mt] = *(const bf16x8*)(p + 512);
    }
#pragma unroll
    for (int nt = 0; nt < 4; nt++) {
      const u16* p = wbase + ((size_t)nt * 64 + kk) * 512;
      bA[nt] = *(const bf16x8*)(p);
      bB[nt] = *(const bf16x8*)(p + 512);
    }
#pragma unroll
    for (int mt = 0; mt < 4; mt++)
#pragma unroll
      for (int nt = 0; nt < 4; nt++)
        acc[mt][nt] = MFMA16(aA[mt], bA[nt], acc[mt][nt], 0, 0, 0);
#pragma unroll
    for (int mt = 0; mt < 4; mt++)
#pragma unroll
      for (int nt = 0; nt < 4; nt++)
        acc[mt][nt] = MFMA16(aB[mt], bB[nt], acc[mt][nt], 0, 0, 0);
  }
  int colbase = bn * 128 + nh * 64;
  float bo4[4];
#pragma unroll
  for (int nt = 0; nt < 4; nt++) bo4[nt] = bo[colbase + nt * 16 + r];
#pragma unroll
  for (int mt = 0; mt < 4; mt++)
#pragma unroll
    for (int nt = 0; nt < 4; nt++)
#pragma unroll
      for (int j = 0; j < 4; j++) acc[mt][nt][j] += bo4[nt];
#pragma unroll
  for (int mt = 0; mt < 4; mt++) {
#pragma unroll
    for (int j = 0; j < 4; j++) {
      float m = fmaxf(fmaxf(acc[mt][0][j], acc[mt][1][j]), fmaxf(acc[mt][2][j], acc[mt][3][j]));
      m = fmaxf(m, __shfl_xor(m, 1));
      m = fmaxf(m, __shfl_xor(m, 2));
      m = fmaxf(m, __shfl_xor(m, 4));
      m = fmaxf(m, __shfl_xor(m, 8));
      float s = expf(acc[mt][0][j] - m) + expf(acc[mt][1][j] - m) +
                expf(acc[mt][2][j] - m) + expf(acc[mt][3][j] - m);
      s += __shfl_xor(s, 1);
      s += __shfl_xor(s, 2);
      s += __shfl_xor(s, 4);
      s += __shfl_xor(s, 8);
      int lrow = mh * 64 + mt * 16 + q * 4 + j;
      if (r == 0) { pmp[nh][lrow] = m; psp[nh][lrow] = s; }
      int tc = tgtc[lrow];
      int off = tc - (bn * 128 + nh * 64);
      if (off >= 0 && off < 64 && (off & 15) == r) {
        tgtlog[bm * 128 + lrow] = acc[mt][off >> 4][j];
      }
    }
  }
  __syncthreads();
  if (tid < 128) {
    int gm = bm * 128 + tid;
    if (gm < M) {
      float m0 = pmp[0][tid], m1 = pmp[1][tid];
      float m = fmaxf(m0, m1);
      float s = psp[0][tid] * expf(m0 - m) + psp[1][tid] * expf(m1 - m);
      pm[(size_t)bn * NR + gm] = m;
      ps[(size_t)bn * NR + gm] = s;
    }
  }
}

// ---------------- merge per-chunk lse partials (compact rows) ----------------
__global__ void lse_combine_kernel(const float* __restrict__ pm, const float* __restrict__ ps,
                                   const float* __restrict__ tgtlog,
                                   const unsigned* __restrict__ mcnt,
                                   float* __restrict__ rowval) {
  int cr = blockIdx.x * blockDim.x + threadIdx.x;
  if (cr >= NR) return;
  if ((unsigned)cr >= mcnt[0]) { rowval[cr] = 0.f; return; }
  float m = -1e30f;
  for (int i = 0; i < NCT; i++) m = fmaxf(m, pm[(size_t)i * NR + cr]);
  float s = 0.f;
  for (int i = 0; i < NCT; i++) s += ps[(size_t)i * NR + cr] * expf(pm[(size_t)i * NR + cr] - m);
  float lse = m + logf(s);
  rowval[cr] = tgtlog[cr] - lse;
}

__global__ void final_reduce_kernel(const float* __restrict__ rowval, float* __restrict__ out) {
  __shared__ float sm[256];
  float s = 0.f;
  for (int i = threadIdx.x; i < NR; i += 256) s += rowval[i];
  sm[threadIdx.x] = s;
  __syncthreads();
  for (int off = 128; off > 0; off >>= 1) {
    if (threadIdx.x < off) sm[threadIdx.x] += sm[threadIdx.x + off];
    __syncthreads();
  }
  if (threadIdx.x == 0) out[0] = sm[0];
}

extern "C" void kernel_launch(void* const* d_in, const int* in_sizes, int n_in,
                              void* d_out, int out_size, void* d_ws, size_t ws_size,
                              hipStream_t stream) {
  const int* src_tokens = (const int*)d_in[0];
  const int* src_lens = (const int*)d_in[1];
  const int* trg_tokens = (const int*)d_in[2];
  const int* trg_lens = (const int*)d_in[3];
  const float* src_emb = (const float*)d_in[4];
  const float* trg_emb = (const float*)d_in[5];
  const float* We_ih = (const float*)d_in[6];
  const float* We_hh = (const float*)d_in[7];
  const float* be_ih = (const float*)d_in[8];
  const float* be_hh = (const float*)d_in[9];
  const float* Wr_ih = (const float*)d_in[10];
  const float* Wr_hh = (const float*)d_in[11];
  const float* br_ih = (const float*)d_in[12];
  const float* br_hh = (const float*)d_in[13];
  const float* Wd_ih = (const float*)d_in[14];
  const float* Wd_hh = (const float*)d_in[15];
  const float* bd_ih = (const float*)d_in[16];
  const float* bd_hh = (const float*)d_in[17];
  const float* W_out = (const float*)d_in[18];
  const float* b_out = (const float*)d_in[19];

  char* base = (char*)d_ws;
  size_t off = 0;
  auto alloc = [&](size_t bytes) -> char* {
    char* p = base + off;
    off += (bytes + 255) & ~(size_t)255;
    return p;
  };
  u16* xsrcb = (u16*)alloc((size_t)2048 * 512 * 2);
  u16* xtrgb = (u16*)alloc((size_t)NR * 512 * 2);
  u16* Wihe = (u16*)alloc((size_t)2048 * 512 * 2);
  u16* Wihr = (u16*)alloc((size_t)2048 * 512 * 2);
  u16* Wihd = (u16*)alloc((size_t)4096 * 512 * 2);
  u16* Wbf_e = (u16*)alloc((size_t)4096 * 512 * 2);
  u16* Wfragd = (u16*)alloc((size_t)4096 * 1024 * 2);
  u16* Wofrag = (u16*)alloc((size_t)NV * 2048 * 2);
  u16* Yfrag = (u16*)alloc((size_t)128 * 64 * 64 * 8 * 2);
  float* Aef = (float*)alloc((size_t)2048 * 2048 * 4);
  float* Aer = (float*)alloc((size_t)2048 * 2048 * 4);
  float* Ad  = (float*)alloc((size_t)NR * 4096 * 4);
  u16* ssb  = (u16*)alloc((size_t)NB * NS * NHD * 2);
  u16* Ybf = (u16*)alloc((size_t)NR * 2048 * 2);
  u16* hbf_e = (u16*)alloc((size_t)4 * 32 * 512 * 2);
  u16* hbf_d = (u16*)alloc((size_t)2 * 32 * NHD * 2);
  float* pm = (float*)alloc((size_t)NCT * NR * 4);
  float* ps = (float*)alloc((size_t)NCT * NR * 4);
  float* tgtlog = (float*)alloc((size_t)NR * 4);
  float* rowval = (float*)alloc((size_t)NR * 4);
  unsigned* flags = (unsigned*)alloc(RECB * FSTRIDE * 4);
  unsigned* rowmap = (unsigned*)alloc(2048 * 4);
  unsigned* mcnt = (unsigned*)alloc(256);

  // fused prologue: gathers + all weight converts + dec-frag + Wo-frag + rowmap + flag init
  prep_kernel<<<38138, 256, 0, stream>>>(
      src_tokens, trg_tokens, trg_lens, src_emb, trg_emb,
      We_ih, Wr_ih, Wd_ih, We_hh, Wr_hh, Wd_hh, W_out,
      xsrcb, xtrgb, Wihe, Wihr, Wihd, Wbf_e, Wfragd, Wofrag, rowmap, mcnt, flags);

  // all three input-gate GEMMs in one launch
  mfma_gemm3<<<dim3(16, 64), 256, 0, stream>>>(
      xsrcb, xtrgb, Wihe, Wihr, Wihd,
      be_ih, be_hh, br_ih, br_hh, bd_ih, bd_hh, Aef, Aer, Ad);

  // full recurrence (spread flags)
  recurrence_kernel<<<RECB, 256, 0, stream>>>(Wbf_e, Wfragd, Aef, Aer, Ad, src_lens,
                                              ssb, Ybf, hbf_e, hbf_d, flags);

  // attention (compact rows; h from Ybf bf16)
  attn_kernel<<<NR, 256, 0, stream>>>(Ybf, ssb, src_lens, rowmap, mcnt, Ybf);

  // repack Y into fragment layout (rowmap folded in)
  yfrag_repack<<<2048, 256, 0, stream>>>(Ybf, rowmap, Yfrag);

  // fused bf16-MFMA logits GEMM + chunked logsumexp
  gemmlse_mfma<<<4000, 256, 0, stream>>>(Yfrag, Wofrag, b_out, trg_tokens, rowmap, mcnt, pm, ps, tgtlog);
  lse_combine_kernel<<<(NR + 255) / 256, 256, 0, stream>>>(pm, ps, tgtlog, mcnt, rowval);
  final_reduce_kernel<<<1, 256, 0, stream>>>(rowval, (float*)d_out);
}

// Round 15
// 1137.796 us; speedup vs baseline: 1.2372x; 1.0174x over previous
//
#include <hip/hip_runtime.h>
#include <math.h>

#define NB 32      // batch
#define NS 64      // src len
#define NT 64      // trg len
#define NHD 1024   // dec hidden
#define NV 32000
#define NR 2016    // (NT-1)*NB
#define NCT 250    // 32000/128
#define RECB 64    // recurrence blocks
#define FSTRIDE 16 // flag stride in u32 (64B line per flag)

typedef unsigned short u16;
typedef __bf16 bf16x8 __attribute__((ext_vector_type(8)));
typedef float f32x4 __attribute__((ext_vector_type(4)));
typedef unsigned u32x4 __attribute__((ext_vector_type(4)));
#define MFMA16 __builtin_amdgcn_mfma_f32_16x16x32_bf16

__device__ __forceinline__ float sigmf(float x) { return 1.f / (1.f + expf(-x)); }
__device__ __forceinline__ u16 f2bf(float f) {
  union { float f; unsigned u; } v; v.f = f;
  unsigned r = v.u + 0x7FFFu + ((v.u >> 16) & 1u);
  return (u16)(r >> 16);
}
__device__ __forceinline__ float bf2f(u16 h) {
  union { unsigned u; float f; } v; v.u = ((unsigned)h) << 16; return v.f;
}

// ---- coherent (cache-bypassing) loads/stores for cross-block data ----
__device__ __forceinline__ u32x4 ldg_coh(const void* p) {
  u32x4 v;
  asm volatile("global_load_dwordx4 %0, %1, off sc0 sc1" : "=v"(v) : "v"(p));
  return v;  // NOT valid until an explicit s_waitcnt vmcnt(0)
}
__device__ __forceinline__ void stg_coh_u32(void* p, unsigned v) {
  asm volatile("global_store_dword %0, %1, off sc0 sc1" :: "v"(p), "v"(v) : "memory");
}
__device__ __forceinline__ unsigned ldg_coh_u32_wait(const void* p) {
  unsigned v;
  asm volatile("global_load_dword %0, %1, off sc0 sc1\n\ts_waitcnt vmcnt(0)"
               : "=v"(v) : "v"(p) : "memory");
  return v;
}
__device__ __forceinline__ void vmwait0() {
  asm volatile("s_waitcnt vmcnt(0)" ::: "memory");
}

__device__ __forceinline__ void cvt8(const float* __restrict__ in, u16* __restrict__ out, long i) {
  float4 a = *(const float4*)(in + i);
  float4 b = *(const float4*)(in + i + 4);
  union { u16 h[8]; uint4 v; } u;
  u.h[0]=f2bf(a.x); u.h[1]=f2bf(a.y); u.h[2]=f2bf(a.z); u.h[3]=f2bf(a.w);
  u.h[4]=f2bf(b.x); u.h[5]=f2bf(b.y); u.h[6]=f2bf(b.z); u.h[7]=f2bf(b.w);
  *(uint4*)(out + i) = u.v;
}

// ---------------- fused prologue: gathers + weight cvts + dec-frag + Wo-frag + rowmap + flags ----------------
__global__ __launch_bounds__(256) void prep_kernel(
    const int* __restrict__ src_tokens, const int* __restrict__ trg_tokens,
    const int* __restrict__ trg_lens,
    const float* __restrict__ src_emb, const float* __restrict__ trg_emb,
    const float* __restrict__ We_ih, const float* __restrict__ Wr_ih,
    const float* __restrict__ Wd_ih, const float* __restrict__ We_hh,
    const float* __restrict__ Wr_hh, const float* __restrict__ Wd_hh,
    const float* __restrict__ W_out,
    u16* __restrict__ xsrcb, u16* __restrict__ xtrgb,
    u16* __restrict__ Wihe, u16* __restrict__ Wihr, u16* __restrict__ Wihd,
    u16* __restrict__ Wbf_e, u16* __restrict__ Wfragd, u16* __restrict__ Wofrag,
    unsigned* __restrict__ rowmap, unsigned* __restrict__ mcnt, unsigned* __restrict__ flags) {
  int b = blockIdx.x, tid = threadIdx.x;
  if (b < 512) {                       // gather_src: 2048*64 chunks
    int idx = b * 256 + tid;
    int m = idx >> 6, c8 = (idx & 63) * 8;
    const float4* s = (const float4*)(src_emb + (size_t)src_tokens[m] * 512 + c8);
    float4 a = s[0], bb = s[1];
    union { u16 h[8]; uint4 v; } u;
    u.h[0]=f2bf(a.x); u.h[1]=f2bf(a.y); u.h[2]=f2bf(a.z); u.h[3]=f2bf(a.w);
    u.h[4]=f2bf(bb.x); u.h[5]=f2bf(bb.y); u.h[6]=f2bf(bb.z); u.h[7]=f2bf(bb.w);
    *(uint4*)(xsrcb + (size_t)m * 512 + c8) = u.v;
  } else if (b < 1016) {               // gather_trg: NR*64 = 129024 = 504*256 chunks
    int idx = (b - 512) * 256 + tid;
    int m = idx >> 6, c8 = (idx & 63) * 8;
    int t = m >> 5, bb2 = m & 31;
    int token = trg_tokens[bb2 * NT + t];
    const float4* s = (const float4*)(trg_emb + (size_t)token * 512 + c8);
    float4 a = s[0], bb = s[1];
    union { u16 h[8]; uint4 v; } u;
    u.h[0]=f2bf(a.x); u.h[1]=f2bf(a.y); u.h[2]=f2bf(a.z); u.h[3]=f2bf(a.w);
    u.h[4]=f2bf(bb.x); u.h[5]=f2bf(bb.y); u.h[6]=f2bf(bb.z); u.h[7]=f2bf(bb.w);
    *(uint4*)(xtrgb + (size_t)m * 512 + c8) = u.v;
  } else if (b < 1528) {               // We_ih -> Wihe
    cvt8(We_ih, Wihe, ((long)(b - 1016) * 256 + tid) * 8);
  } else if (b < 2040) {               // Wr_ih -> Wihr
    cvt8(Wr_ih, Wihr, ((long)(b - 1528) * 256 + tid) * 8);
  } else if (b < 3064) {               // Wd_ih -> Wihd
    cvt8(Wd_ih, Wihd, ((long)(b - 2040) * 256 + tid) * 8);
  } else if (b < 3576) {               // We_hh -> Wbf_e[0:]
    cvt8(We_hh, Wbf_e, ((long)(b - 3064) * 256 + tid) * 8);
  } else if (b < 4088) {               // Wr_hh -> Wbf_e[2048*512:]
    cvt8(Wr_hh, Wbf_e + (size_t)2048 * 512, ((long)(b - 3576) * 256 + tid) * 8);
  } else if (b < 6136) {               // Wd_hh -> dec fragment layout (524288 chunks)
    int idx = (b - 4088) * 256 + tid;
    int lane = idx & 63;
    int kk = (idx >> 6) & 31;
    int g = (idx >> 11) & 3;
    int jt = idx >> 13;
    int row = g * 1024 + jt * 16 + (lane & 15);
    int col = kk * 32 + (lane >> 4) * 8;
    const float4* s = (const float4*)(Wd_hh + (size_t)row * NHD + col);
    float4 a = s[0], bb = s[1];
    union { u16 h[8]; uint4 v; } u;
    u.h[0]=f2bf(a.x); u.h[1]=f2bf(a.y); u.h[2]=f2bf(a.z); u.h[3]=f2bf(a.w);
    u.h[4]=f2bf(bb.x); u.h[5]=f2bf(bb.y); u.h[6]=f2bf(bb.z); u.h[7]=f2bf(bb.w);
    *(uint4*)(Wfragd + (size_t)idx * 8) = u.v;
  } else if (b == 6136) {              // rowmap + mcnt
    __shared__ unsigned P[32];
    for (int i = tid; i < 2048; i += 256) rowmap[i] = 0u;
    if (tid == 0) {
      unsigned acc = 0;
      for (int bb2 = 0; bb2 < 32; bb2++) {
        P[bb2] = acc;
        int L = trg_lens[bb2]; if (L > NT) L = NT;
        acc += (unsigned)(L - 1);
      }
      mcnt[0] = acc;
    }
    __syncthreads();
    for (int bb2 = 0; bb2 < 32; bb2++) {
      int L = trg_lens[bb2]; if (L > NT) L = NT;
      int Lb = L - 1;
      if (tid < Lb) rowmap[P[bb2] + tid] = (unsigned)(tid * 32 + bb2);
    }
  } else if (b == 6137) {              // flag init (spread, 64B stride)
    if (tid < RECB) flags[tid * FSTRIDE] = 0u;
  } else {                             // b >= 6138: W_out -> fragment layout (8,192,000 chunks)
    long idx = (long)(b - 6138) * 256 + tid;
    int lane = (int)(idx & 63);
    int kk = (int)((idx >> 6) & 63);
    long j16 = idx >> 12;
    long row = j16 * 16 + (lane & 15);
    int col = kk * 32 + (lane >> 4) * 8;
    const float4* s = (const float4*)(W_out + (size_t)row * 2048 + col);
    float4 a = s[0], bb = s[1];
    union { u16 h[8]; uint4 v; } u;
    u.h[0]=f2bf(a.x); u.h[1]=f2bf(a.y); u.h[2]=f2bf(a.z); u.h[3]=f2bf(a.w);
    u.h[4]=f2bf(bb.x); u.h[5]=f2bf(bb.y); u.h[6]=f2bf(bb.z); u.h[7]=f2bf(bb.w);
    *(uint4*)(Wofrag + (size_t)idx * 8) = u.v;
  }
}

// ---------------- combined input-gate GEMMs (Aef | Aer | Ad) ----------------
__global__ __launch_bounds__(256) void mfma_gemm3(
    const u16* __restrict__ xsrcb, const u16* __restrict__ xtrgb,
    const u16* __restrict__ Wihe, const u16* __restrict__ Wihr, const u16* __restrict__ Wihd,
    const float* __restrict__ be_ih, const float* __restrict__ be_hh,
    const float* __restrict__ br_ih, const float* __restrict__ br_hh,
    const float* __restrict__ bd_ih, const float* __restrict__ bd_hh,
    float* __restrict__ Aef, float* __restrict__ Aer, float* __restrict__ Ad) {
  int by = blockIdx.y;
  const u16 *A, *Bm; const float *b0, *b1; float* C; int M, N, colTile;
  if (by < 16)      { A = xsrcb; Bm = Wihe; b0 = be_ih; b1 = be_hh; C = Aef; M = 2048; N = 2048; colTile = by; }
  else if (by < 32) { A = xsrcb; Bm = Wihr; b0 = br_ih; b1 = br_hh; C = Aer; M = 2048; N = 2048; colTile = by - 16; }
  else              { A = xtrgb; Bm = Wihd; b0 = bd_ih; b1 = bd_hh; C = Ad;  M = NR;   N = 4096; colTile = by - 32; }
  int tid = threadIdx.x, wave = tid >> 6, lane = tid & 63;
  int r = lane & 15, q = lane >> 4;
  int mh = wave >> 1, nh = wave & 1;
  int rowbase = blockIdx.x * 128 + mh * 64;
  int colbase = colTile * 128 + nh * 64;
  f32x4 acc[4][4] = {};
  for (int k0 = 0; k0 < 512; k0 += 32) {
    bf16x8 a[4], b[4];
#pragma unroll
    for (int mt = 0; mt < 4; mt++) {
      int rb = rowbase + mt * 16 + r;
      if (rb >= M) rb = 0;
      a[mt] = *(const bf16x8*)(A + (size_t)rb * 512 + k0 + q * 8);
    }
#pragma unroll
    for (int nt = 0; nt < 4; nt++)
      b[nt] = *(const bf16x8*)(Bm + (size_t)(colbase + nt * 16 + r) * 512 + k0 + q * 8);
#pragma unroll
    for (int mt = 0; mt < 4; mt++)
#pragma unroll
      for (int nt = 0; nt < 4; nt++)
        acc[mt][nt] = MFMA16(a[mt], b[nt], acc[mt][nt], 0, 0, 0);
  }
#pragma unroll
  for (int nt = 0; nt < 4; nt++) {
    int gn = colbase + nt * 16 + r;
    float bb = b0[gn] + b1[gn];
#pragma unroll
    for (int mt = 0; mt < 4; mt++)
#pragma unroll
      for (int j = 0; j < 4; j++) {
        int gm = rowbase + mt * 16 + q * 4 + j;
        if (gm < M) C[(size_t)gm * N + gn] = acc[mt][nt][j] + bb;
      }
  }
}

// ---------------- persistent recurrence (split SIGNAL/WAIT barrier, all-waves poll) ----------------
#define ENC_H_OFF 65536
#define ENC_G_OFF 98304
#define DEC_G_OFF 65536
__global__ __launch_bounds__(256, 1) void recurrence_kernel(
    const u16* __restrict__ Wbf_e,    // [4096][512] (fwd 0..2047, rev 2048..)
    const u16* __restrict__ Wfragd,   // dec W fragment layout, 8MB
    const float* __restrict__ Aef, const float* __restrict__ Aer, const float* __restrict__ Ad,
    const int* __restrict__ src_lens,
    u16* __restrict__ ssb, u16* __restrict__ Ybf,
    u16* __restrict__ hbf_e,   // [2 parity][2 lstm][32][512] bf16 (coherent)
    u16* __restrict__ hbf_d,   // [2 parity][32][1024] bf16 (coherent)
    unsigned* flags) {
  __shared__ __align__(16) char smem[107008];
  const int tid = threadIdx.x, bid = blockIdx.x;
  const int wave = tid >> 6, lane = tid & 63;
  const int r = lane & 15, q = lane >> 4;
  const int g = wave;
  const int ob = tid >> 3;        // epilogue batch
  const int oj = (tid & 7) * 2;   // epilogue col pair within 16
  const int slen_ob = src_lens[ob];
  unsigned tgt = 0;

  // SIGNAL: all waves' stores drained (vmwait + sync), then one flag store.
#define SIGNAL()                                                                   \
  do {                                                                             \
    tgt++;                                                                         \
    vmwait0();                                                                     \
    __syncthreads();                                                               \
    if (tid == 0) stg_coh_u32(flags + bid * FSTRIDE, tgt);                         \
  } while (0)

  // WAIT: every wave polls independently; no trailing block sync (each wave
  // proceeds straight to its staging loads; the pre-MFMA __syncthreads orders LDS).
#define WAITG(fbase, fcnt)                                                         \
  do {                                                                             \
    unsigned fv = tgt;                                                             \
    do {                                                                           \
      if (lane < (fcnt)) fv = ldg_coh_u32_wait(flags + ((fbase) + lane) * FSTRIDE);\
    } while (__any(fv < tgt));                                                     \
  } while (0)

  // ================= encoder =================
  {
    const int lstm = bid >> 5, jt = bid & 31;
    float* gates = (float*)(smem + ENC_G_OFF);
    for (int c = tid; c < 64 * 64; c += 256) {
      int lr = c >> 6, c8 = (c & 63) * 8;
      int grow = lstm * 2048 + (lr >> 4) * 512 + jt * 16 + (lr & 15);
      uint4 v = *(const uint4*)(Wbf_e + (size_t)grow * 512 + c8);
      *(uint4*)(smem + ((lr * 1024 + c8 * 2) ^ ((lr & 7) << 4))) = v;
    }
    const float* Ae = lstm ? Aer : Aef;
    const int jcol = jt * 16 + oj;
    float creg0 = 0.f, creg1 = 0.f;
    for (int t = 0; t < NS; t++) {
      size_t abase = ((size_t)ob * NS + t) * 2048;
      float2 vi = *(const float2*)(Ae + abase + jcol);
      float2 vf = *(const float2*)(Ae + abase + 512 + jcol);
      float2 vg = *(const float2*)(Ae + abase + 1024 + jcol);
      float2 vo = *(const float2*)(Ae + abase + 1536 + jcol);
      if (t == 0) {
        u32x4 z = {0u, 0u, 0u, 0u};
#pragma unroll
        for (int k = 0; k < 8; k++) {
          int c = tid + k * 256;
          int hr = c >> 6, seg = c & 63;
          *(u32x4*)(smem + (ENC_H_OFF + ((hr * 1024 + seg * 16) ^ ((hr & 7) << 4)))) = z;
        }
      } else {
        const u16* hsrc = hbf_e + ((size_t)(t & 1) * 2 + lstm) * 16384;
        u32x4 hv[8];
#pragma unroll
        for (int k = 0; k < 8; k++) hv[k] = ldg_coh(hsrc + (tid + k * 256) * 8);
        vmwait0();
#pragma unroll
        for (int k = 0; k < 8; k++) {
          int c = tid + k * 256;
          int hr = c >> 6, seg = c & 63;
          *(u32x4*)(smem + (ENC_H_OFF + ((hr * 1024 + seg * 16) ^ ((hr & 7) << 4)))) = hv[k];
        }
      }
      __syncthreads();
      f32x4 acc0 = {0.f,0.f,0.f,0.f}, acc1 = {0.f,0.f,0.f,0.f};
      for (int ks = 0; ks < 512; ks += 32) {
        int col2 = (ks + q * 8) * 2;
        int a0r = r, a1r = 16 + r, br = g * 16 + r;
        bf16x8 a0 = *(const bf16x8*)(smem + (ENC_H_OFF + ((a0r * 1024 + col2) ^ ((a0r & 7) << 4))));
        bf16x8 a1 = *(const bf16x8*)(smem + (ENC_H_OFF + ((a1r * 1024 + col2) ^ ((a1r & 7) << 4))));
        bf16x8 bf = *(const bf16x8*)(smem + ((br * 1024 + col2) ^ ((br & 7) << 4)));
        acc0 = MFMA16(a0, bf, acc0, 0, 0, 0);
        acc1 = MFMA16(a1, bf, acc1, 0, 0, 0);
      }
#pragma unroll
      for (int j = 0; j < 4; j++) {
        gates[(g * 32 + q * 4 + j) * 17 + r] = acc0[j];
        gates[(g * 32 + 16 + q * 4 + j) * 17 + r] = acc1[j];
      }
      __syncthreads();
      {
        float I0 = vi.x + gates[(0 * 32 + ob) * 17 + oj];
        float I1 = vi.y + gates[(0 * 32 + ob) * 17 + oj + 1];
        float F0 = vf.x + gates[(1 * 32 + ob) * 17 + oj];
        float F1 = vf.y + gates[(1 * 32 + ob) * 17 + oj + 1];
        float G0 = vg.x + gates[(2 * 32 + ob) * 17 + oj];
        float G1 = vg.y + gates[(2 * 32 + ob) * 17 + oj + 1];
        float O0 = vo.x + gates[(3 * 32 + ob) * 17 + oj];
        float O1 = vo.y + gates[(3 * 32 + ob) * 17 + oj + 1];
        float c0 = sigmf(F0) * creg0 + sigmf(I0) * tanhf(G0);
        float c1 = sigmf(F1) * creg1 + sigmf(I1) * tanhf(G1);
        float h0 = sigmf(O0) * tanhf(c0);
        float h1 = sigmf(O1) * tanhf(c1);
        creg0 = c0; creg1 = c1;
        unsigned hv2 = ((unsigned)f2bf(h1) << 16) | f2bf(h0);
        stg_coh_u32(hbf_e + ((size_t)((t + 1) & 1) * 2 + lstm) * 16384 + ob * 512 + jcol, hv2);
        *(unsigned*)(ssb + ((size_t)ob * NS + t) * NHD + lstm * 512 + jcol) = hv2;
        if (t == slen_ob - 1)
          stg_coh_u32(hbf_d + ob * NHD + lstm * 512 + jcol, hv2);
      }
      if (t < NS - 1) {           // final encoder step folds into the phase barrier
        SIGNAL();
        WAITG(lstm * 32, 32);
      }
    }
  }

  // phase barrier: all encoder output (hbf_d, ssb) visible to every block
  SIGNAL();
  WAITG(0, RECB);

  // ================= decoder =================
  {
    const int jt = bid;
    const int jcol = jt * 16 + oj;
    float* gates = (float*)(smem + DEC_G_OFF);
    const u16* wbase = Wfragd + (size_t)(jt * 4 + g) * 16384;
    float cd0 = 0.f, cd1 = 0.f;
    for (int t = 0; t < NT - 1; t++) {
      const float* ad = Ad + ((size_t)t * NB + ob) * 4096;
      float2 vi = *(const float2*)(ad + jcol);
      float2 vf = *(const float2*)(ad + 1024 + jcol);
      float2 vg = *(const float2*)(ad + 2048 + jcol);
      float2 vo = *(const float2*)(ad + 3072 + jcol);
      const u16* hsrc = hbf_d + (size_t)(t & 1) * (32 * NHD);
      {
        u32x4 hv[16];
#pragma unroll
        for (int k = 0; k < 16; k++) hv[k] = ldg_coh(hsrc + (tid + k * 256) * 8);
        vmwait0();
#pragma unroll
        for (int k = 0; k < 16; k++) {
          int c = tid + k * 256;
          int hr = c >> 7, seg = c & 127;
          *(u32x4*)(smem + ((hr * 2048 + seg * 16) ^ ((hr & 7) << 4))) = hv[k];
        }
      }
      __syncthreads();
      f32x4 acc0 = {0.f,0.f,0.f,0.f}, acc1 = {0.f,0.f,0.f,0.f};
      for (int kk = 0; kk < 32; kk++) {
        int colb = (kk * 32 + q * 8) * 2;
        int a0r = r, a1r = 16 + r;
        bf16x8 a0 = *(const bf16x8*)(smem + ((a0r * 2048 + colb) ^ ((a0r & 7) << 4)));
        bf16x8 a1 = *(const bf16x8*)(smem + ((a1r * 2048 + colb) ^ ((a1r & 7) << 4)));
        bf16x8 bf = *(const bf16x8*)(wbase + ((size_t)kk * 64 + lane) * 8);
        acc0 = MFMA16(a0, bf, acc0, 0, 0, 0);
        acc1 = MFMA16(a1, bf, acc1, 0, 0, 0);
      }
#pragma unroll
      for (int j = 0; j < 4; j++) {
        gates[(g * 32 + q * 4 + j) * 17 + r] = acc0[j];
        gates[(g * 32 + 16 + q * 4 + j) * 17 + r] = acc1[j];
      }
      __syncthreads();
      {
        float I0 = vi.x + gates[(0 * 32 + ob) * 17 + oj];
        float I1 = vi.y + gates[(0 * 32 + ob) * 17 + oj + 1];
        float F0 = vf.x + gates[(1 * 32 + ob) * 17 + oj];
        float F1 = vf.y + gates[(1 * 32 + ob) * 17 + oj + 1];
        float G0 = vg.x + gates[(2 * 32 + ob) * 17 + oj];
        float G1 = vg.y + gates[(2 * 32 + ob) * 17 + oj + 1];
        float O0 = vo.x + gates[(3 * 32 + ob) * 17 + oj];
        float O1 = vo.y + gates[(3 * 32 + ob) * 17 + oj + 1];
        float c0 = sigmf(F0) * cd0 + sigmf(I0) * tanhf(G0);
        float c1 = sigmf(F1) * cd1 + sigmf(I1) * tanhf(G1);
        float h0 = sigmf(O0) * tanhf(c0);
        float h1 = sigmf(O1) * tanhf(c1);
        cd0 = c0; cd1 = c1;
        size_t rowY = (size_t)t * NB + ob;
        unsigned hv2 = ((unsigned)f2bf(h1) << 16) | f2bf(h0);
        stg_coh_u32(hbf_d + (size_t)((t + 1) & 1) * (32 * NHD) + ob * NHD + jcol, hv2);
        *(unsigned*)(Ybf + rowY * 2048 + jcol) = hv2;
      }
      if (t != NT - 2) {
        SIGNAL();
        WAITG(0, RECB);
      }
    }
  }
#undef SIGNAL
#undef WAITG
}

// ---------------- attention (compact rows; h read from Ybf bf16) ----------------
__global__ __launch_bounds__(256) void attn_kernel(const u16* __restrict__ Ybf_in,
                                                   const u16* __restrict__ ssb,
                                                   const int* __restrict__ src_lens,
                                                   const unsigned* __restrict__ rowmap,
                                                   const unsigned* __restrict__ mcnt,
                                                   u16* __restrict__ Ybf) {
  __shared__ __align__(16) float hsh[NHD];
  __shared__ float sc[NS];
  __shared__ float att[NS];
  int cr = blockIdx.x;
  if ((unsigned)cr >= mcnt[0]) return;
  int rr = (int)rowmap[cr];
  int b = rr & 31;
  int tid = threadIdx.x;
  {
    int i = tid * 4;  // 256 threads x 4 = 1024
    uint2 v = *(const uint2*)(Ybf_in + (size_t)rr * 2048 + i);
    hsh[i + 0] = bf2f((u16)(v.x & 0xFFFF));
    hsh[i + 1] = bf2f((u16)(v.x >> 16));
    hsh[i + 2] = bf2f((u16)(v.y & 0xFFFF));
    hsh[i + 3] = bf2f((u16)(v.y >> 16));
  }
  __syncthreads();
  {
    int s = tid >> 2, q = tid & 3;
    const u16* row = ssb + ((size_t)b * NS + s) * NHD + q * 256;
    const float* h4 = hsh + q * 256;
    float p = 0.f;
    for (int k = 0; k < 256; k += 8) {
      uint4 v = *(const uint4*)(row + k);
      p += h4[k + 0] * bf2f((u16)(v.x & 0xFFFF)) + h4[k + 1] * bf2f((u16)(v.x >> 16));
      p += h4[k + 2] * bf2f((u16)(v.y & 0xFFFF)) + h4[k + 3] * bf2f((u16)(v.y >> 16));
      p += h4[k + 4] * bf2f((u16)(v.z & 0xFFFF)) + h4[k + 5] * bf2f((u16)(v.z >> 16));
      p += h4[k + 6] * bf2f((u16)(v.w & 0xFFFF)) + h4[k + 7] * bf2f((u16)(v.w >> 16));
    }
    p += __shfl_xor(p, 1);
    p += __shfl_xor(p, 2);
    if (q == 0) sc[s] = (s < src_lens[b]) ? p : -1e9f;
  }
  __syncthreads();
  if (tid < 64) {
    float v = sc[tid];
    float m = v;
#pragma unroll
    for (int off = 1; off < 64; off <<= 1) m = fmaxf(m, __shfl_xor(m, off));
    float e = expf(v - m);
    float ssum = e;
#pragma unroll
    for (int off = 1; off < 64; off <<= 1) ssum += __shfl_xor(ssum, off);
    att[tid] = e / ssum;
  }
  __syncthreads();
  float a0 = 0, a1 = 0, a2 = 0, a3 = 0;
  int d = tid * 4;
  for (int s2 = 0; s2 < NS; s2++) {
    float a = att[s2];
    uint2 v = *(const uint2*)(ssb + ((size_t)b * NS + s2) * NHD + d);
    a0 += a * bf2f((u16)(v.x & 0xFFFF));
    a1 += a * bf2f((u16)(v.x >> 16));
    a2 += a * bf2f((u16)(v.y & 0xFFFF));
    a3 += a * bf2f((u16)(v.y >> 16));
  }
  ushort4 o;
  o.x = f2bf(a0); o.y = f2bf(a1); o.z = f2bf(a2); o.w = f2bf(a3);
  *(ushort4*)(Ybf + (size_t)rr * 2048 + NHD + d) = o;
}

// ---------------- Ybf -> fragment layout (rowmap folded in) ----------------
__global__ void yfrag_repack(const u16* __restrict__ Ybf, const unsigned* __restrict__ rowmap,
                             u16* __restrict__ out) {
  int idx = blockIdx.x * 256 + threadIdx.x;  // 524288 chunks
  if (idx >= 128 * 64 * 64) return;
  int lane = idx & 63;
  int kk = (idx >> 6) & 63;
  int im = idx >> 12;
  int rr = (int)rowmap[im * 16 + (lane & 15)];
  int col = kk * 32 + (lane >> 4) * 8;
  *(uint4*)(out + (size_t)idx * 8) = *(const uint4*)(Ybf + (size_t)rr * 2048 + col);
}

// ---------------- MFMA logits GEMM (fragment-layout operands) + fused LSE ----------------
__global__ __launch_bounds__(256) void gemmlse_mfma(
    const u16* __restrict__ Yf,   // Yfrag: [128 m-tiles][64 kk][64 lanes][8]
    const u16* __restrict__ Wf,   // Wofrag: [2000 n-tiles][64 kk][64 lanes][8]
    const float* __restrict__ bo, const int* __restrict__ trg_tok,
    const unsigned* __restrict__ rowmap, const unsigned* __restrict__ mcnt,
    float* __restrict__ pm, float* __restrict__ ps, float* __restrict__ tgtlog) {
  __shared__ int tgtc[128];
  __shared__ float pmp[2][128];
  __shared__ float psp[2][128];
  int o = blockIdx.x;
  int u = (o & 7) * 500 + (o >> 3);
  int bm = u & 15, bn = u >> 4;
  const int M = (int)mcnt[0];
  if (bm * 128 >= M) return;
  int tid = threadIdx.x;
  int wave = tid >> 6, lane = tid & 63;
  int r = lane & 15, q = lane >> 4;
  int mh = wave >> 1, nh = wave & 1;
  if (tid < 128) {
    int gm = bm * 128 + tid;
    if (gm < M) {
      int rr = (int)rowmap[gm];
      int tt = rr >> 5, b = rr & 31;
      tgtc[tid] = trg_tok[b * NT + tt + 1];
    } else {
      tgtc[tid] = -1;
    }
  }
  __syncthreads();
  const u16* ybase = Yf + (((size_t)(bm * 8 + mh * 4) * 64) * 64 + lane) * 8;
  const u16* wbase = Wf + (((size_t)(bn * 8 + nh * 4) * 64) * 64 + lane) * 8;
  f32x4 acc[4][4] = {};
  for (int kk = 0; kk < 64; kk += 2) {
    bf16x8 aA[4], bA[4], aB[4], bB[4];
#pragma unroll
    for (int mt = 0; mt < 4; mt++) {
      const u16* p = ybase + ((size_t)mt * 64 + kk) * 512;
      aA[mt] = *(const bf16x8*)(p);
      aB[mt] = *(const bf16x8*)(p + 512);
    }
#pragma unroll
    for (int nt = 0; nt < 4; nt++) {
      const u16* p = wbase + ((size_t)nt * 64 + kk) * 512;
      bA[nt] = *(const bf16x8*)(p);
      bB[nt] = *(const bf16x8*)(p + 512);
    }
#pragma unroll
    for (int mt = 0; mt < 4; mt++)
#pragma unroll
      for (int nt = 0; nt < 4; nt++)
        acc[mt][nt] = MFMA16(aA[mt], bA[nt], acc[mt][nt], 0, 0, 0);
#pragma unroll
    for (int mt = 0; mt < 4; mt++)
#pragma unroll
      for (int nt = 0; nt < 4; nt++)
        acc[mt][nt] = MFMA16(aB[mt], bB[nt], acc[mt][nt], 0, 0, 0);
  }
  int colbase = bn * 128 + nh * 64;
  float bo4[4];
#pragma unroll
  for (int nt = 0; nt < 4; nt++) bo4[nt] = bo[colbase + nt * 16 + r];
#pragma unroll
  for (int mt = 0; mt < 4; mt++)
#pragma unroll
    for (int nt = 0; nt < 4; nt++)
#pragma unroll
      for (int j = 0; j < 4; j++) acc[mt][nt][j] += bo4[nt];
#pragma unroll
  for (int mt = 0; mt < 4; mt++) {
#pragma unroll
    for (int j = 0; j < 4; j++) {
      float m = fmaxf(fmaxf(acc[mt][0][j], acc[mt][1][j]), fmaxf(acc[mt][2][j], acc[mt][3][j]));
      m = fmaxf(m, __shfl_xor(m, 1));
      m = fmaxf(m, __shfl_xor(m, 2));
      m = fmaxf(m, __shfl_xor(m, 4));
      m = fmaxf(m, __shfl_xor(m, 8));
      float s = expf(acc[mt][0][j] - m) + expf(acc[mt][1][j] - m) +
                expf(acc[mt][2][j] - m) + expf(acc[mt][3][j] - m);
      s += __shfl_xor(s, 1);
      s += __shfl_xor(s, 2);
      s += __shfl_xor(s, 4);
      s += __shfl_xor(s, 8);
      int lrow = mh * 64 + mt * 16 + q * 4 + j;
      if (r == 0) { pmp[nh][lrow] = m; psp[nh][lrow] = s; }
      int tc = tgtc[lrow];
      int off = tc - (bn * 128 + nh * 64);
      if (off >= 0 && off < 64 && (off & 15) == r) {
        tgtlog[bm * 128 + lrow] = acc[mt][off >> 4][j];
      }
    }
  }
  __syncthreads();
  if (tid < 128) {
    int gm = bm * 128 + tid;
    if (gm < M) {
      float m0 = pmp[0][tid], m1 = pmp[1][tid];
      float m = fmaxf(m0, m1);
      float s = psp[0][tid] * expf(m0 - m) + psp[1][tid] * expf(m1 - m);
      pm[(size_t)bn * NR + gm] = m;
      ps[(size_t)bn * NR + gm] = s;
    }
  }
}

// ---------------- merge per-chunk lse partials (compact rows) ----------------
__global__ void lse_combine_kernel(const float* __restrict__ pm, const float* __restrict__ ps,
                                   const float* __restrict__ tgtlog,
                                   const unsigned* __restrict__ mcnt,
                                   float* __restrict__ rowval) {
  int cr = blockIdx.x * blockDim.x + threadIdx.x;
  if (cr >= NR) return;
  if ((unsigned)cr >= mcnt[0]) { rowval[cr] = 0.f; return; }
  float m = -1e30f;
  for (int i = 0; i < NCT; i++) m = fmaxf(m, pm[(size_t)i * NR + cr]);
  float s = 0.f;
  for (int i = 0; i < NCT; i++) s += ps[(size_t)i * NR + cr] * expf(pm[(size_t)i * NR + cr] - m);
  float lse = m + logf(s);
  rowval[cr] = tgtlog[cr] - lse;
}

__global__ void final_reduce_kernel(const float* __restrict__ rowval, float* __restrict__ out) {
  __shared__ float sm[256];
  float s = 0.f;
  for (int i = threadIdx.x; i < NR; i += 256) s += rowval[i];
  sm[threadIdx.x] = s;
  __syncthreads();
  for (int off = 128; off > 0; off >>= 1) {
    if (threadIdx.x < off) sm[threadIdx.x] += sm[threadIdx.x + off];
    __syncthreads();
  }
  if (threadIdx.x == 0) out[0] = sm[0];
}

extern "C" void kernel_launch(void* const* d_in, const int* in_sizes, int n_in,
                              void* d_out, int out_size, void* d_ws, size_t ws_size,
                              hipStream_t stream) {
  const int* src_tokens = (const int*)d_in[0];
  const int* src_lens = (const int*)d_in[1];
  const int* trg_tokens = (const int*)d_in[2];
  const int* trg_lens = (const int*)d_in[3];
  const float* src_emb = (const float*)d_in[4];
  const float* trg_emb = (const float*)d_in[5];
  const float* We_ih = (const float*)d_in[6];
  const float* We_hh = (const float*)d_in[7];
  const float* be_ih = (const float*)d_in[8];
  const float* be_hh = (const float*)d_in[9];
  const float* Wr_ih = (const float*)d_in[10];
  const float* Wr_hh = (const float*)d_in[11];
  const float* br_ih = (const float*)d_in[12];
  const float* br_hh = (const float*)d_in[13];
  const float* Wd_ih = (const float*)d_in[14];
  const float* Wd_hh = (const float*)d_in[15];
  const float* bd_ih = (const float*)d_in[16];
  const float* bd_hh = (const float*)d_in[17];
  const float* W_out = (const float*)d_in[18];
  const float* b_out = (const float*)d_in[19];

  char* base = (char*)d_ws;
  size_t off = 0;
  auto alloc = [&](size_t bytes) -> char* {
    char* p = base + off;
    off += (bytes + 255) & ~(size_t)255;
    return p;
  };
  u16* xsrcb = (u16*)alloc((size_t)2048 * 512 * 2);
  u16* xtrgb = (u16*)alloc((size_t)NR * 512 * 2);
  u16* Wihe = (u16*)alloc((size_t)2048 * 512 * 2);
  u16* Wihr = (u16*)alloc((size_t)2048 * 512 * 2);
  u16* Wihd = (u16*)alloc((size_t)4096 * 512 * 2);
  u16* Wbf_e = (u16*)alloc((size_t)4096 * 512 * 2);
  u16* Wfragd = (u16*)alloc((size_t)4096 * 1024 * 2);
  u16* Wofrag = (u16*)alloc((size_t)NV * 2048 * 2);
  u16* Yfrag = (u16*)alloc((size_t)128 * 64 * 64 * 8 * 2);
  float* Aef = (float*)alloc((size_t)2048 * 2048 * 4);
  float* Aer = (float*)alloc((size_t)2048 * 2048 * 4);
  float* Ad  = (float*)alloc((size_t)NR * 4096 * 4);
  u16* ssb  = (u16*)alloc((size_t)NB * NS * NHD * 2);
  u16* Ybf = (u16*)alloc((size_t)NR * 2048 * 2);
  u16* hbf_e = (u16*)alloc((size_t)4 * 32 * 512 * 2);
  u16* hbf_d = (u16*)alloc((size_t)2 * 32 * NHD * 2);
  float* pm = (float*)alloc((size_t)NCT * NR * 4);
  float* ps = (float*)alloc((size_t)NCT * NR * 4);
  float* tgtlog = (float*)alloc((size_t)NR * 4);
  float* rowval = (float*)alloc((size_t)NR * 4);
  unsigned* flags = (unsigned*)alloc(RECB * FSTRIDE * 4);
  unsigned* rowmap = (unsigned*)alloc(2048 * 4);
  unsigned* mcnt = (unsigned*)alloc(256);

  // fused prologue: gathers + all weight converts + dec-frag + Wo-frag + rowmap + flag init
  prep_kernel<<<38138, 256, 0, stream>>>(
      src_tokens, trg_tokens, trg_lens, src_emb, trg_emb,
      We_ih, Wr_ih, Wd_ih, We_hh, Wr_hh, Wd_hh, W_out,
      xsrcb, xtrgb, Wihe, Wihr, Wihd, Wbf_e, Wfragd, Wofrag, rowmap, mcnt, flags);

  // all three input-gate GEMMs in one launch
  mfma_gemm3<<<dim3(16, 64), 256, 0, stream>>>(
      xsrcb, xtrgb, Wihe, Wihr, Wihd,
      be_ih, be_hh, br_ih, br_hh, bd_ih, bd_hh, Aef, Aer, Ad);

  // full recurrence (split SIGNAL/WAIT, all-waves poll)
  recurrence_kernel<<<RECB, 256, 0, stream>>>(Wbf_e, Wfragd, Aef, Aer, Ad, src_lens,
                                              ssb, Ybf, hbf_e, hbf_d, flags);

  // attention (compact rows; h from Ybf bf16)
  attn_kernel<<<NR, 256, 0, stream>>>(Ybf, ssb, src_lens, rowmap, mcnt, Ybf);

  // repack Y into fragment layout (rowmap folded in)
  yfrag_repack<<<2048, 256, 0, stream>>>(Ybf, rowmap, Yfrag);

  // fused bf16-MFMA logits GEMM + chunked logsumexp
  gemmlse_mfma<<<4000, 256, 0, stream>>>(Yfrag, Wofrag, b_out, trg_tokens, rowmap, mcnt, pm, ps, tgtlog);
  lse_combine_kernel<<<(NR + 255) / 256, 256, 0, stream>>>(pm, ps, tgtlog, mcnt, rowval);
  final_reduce_kernel<<<1, 256, 0, stream>>>(rowval, (float*)d_out);
}